// Round 6
// baseline (136.258 us; speedup 1.0000x reference)
//
#include <hip/hip_runtime.h>
#include <math.h>

#define NN 1024
#define BB 2
#define D 64
#define NHEAD 4
#define PH 16
#define LOG2E 1.4426950408889634f

template <int CTRL>
__device__ __forceinline__ float dpp_mov(float x) {
    int xi = __builtin_bit_cast(int, x);
    int r = __builtin_amdgcn_update_dpp(0, xi, CTRL, 0xF, 0xF, true);
    return __builtin_bit_cast(float, r);
}

// 16-lane row sum; valid in lane 15 of each row of 16.
__device__ __forceinline__ float dpp_rowsum16(float t) {
    t += dpp_mov<0x111>(t);
    t += dpp_mov<0x112>(t);
    t += dpp_mov<0x114>(t);
    t += dpp_mov<0x118>(t);
    return t;
}

// sum across a 4-lane quad via quad_perm butterfly; valid in ALL quad lanes.
__device__ __forceinline__ float quad_sum4(float t) {
    t += dpp_mov<0xB1>(t);   // quad_perm [1,0,3,2]
    t += dpp_mov<0x4E>(t);   // quad_perm [2,3,0,1]
    return t;
}

// async global->LDS, 16B per lane. LDS dest is wave-uniform base + lane*16;
// global src is per-lane. Increments vmcnt only.
__device__ __forceinline__ void gload_lds16(const float* g, float* l) {
    __builtin_amdgcn_global_load_lds(
        (const __attribute__((address_space(1))) unsigned int*)g,
        (__attribute__((address_space(3))) unsigned int*)l,
        16, 0, 0);
}

// --- Kernel 1: adjacency mask as tiled GEMM on RAW embedding rows --------
// norms are positive & finite, so (ne_i.ne_j != 0) <=> (emb_i.emb_j != 0).
#define MST 65
__global__ __launch_bounds__(256) void k_mask(const float* __restrict__ emb,
                                              unsigned char* __restrict__ mask) {
    __shared__ float As[64 * MST];
    __shared__ float Bs[64 * MST];
    int tid = threadIdx.x;
    int ib = (blockIdx.x & 15) << 6;
    int jb = (blockIdx.x >> 4) << 6;

    #pragma unroll
    for (int r = 0; r < 4; ++r) {
        int q = tid + (r << 8);
        int row = q >> 4, c4 = (q & 15) << 2;
        float4 a = *(const float4*)&emb[(ib + row) * D + c4];
        float4 b = *(const float4*)&emb[(jb + row) * D + c4];
        As[row * MST + c4 + 0] = a.x; As[row * MST + c4 + 1] = a.y;
        As[row * MST + c4 + 2] = a.z; As[row * MST + c4 + 3] = a.w;
        Bs[row * MST + c4 + 0] = b.x; Bs[row * MST + c4 + 1] = b.y;
        Bs[row * MST + c4 + 2] = b.z; Bs[row * MST + c4 + 3] = b.w;
    }
    __syncthreads();

    int i0 = (tid >> 4) << 2;
    int j0 = (tid & 15) << 2;
    float acc[4][4] = {};
    #pragma unroll 8
    for (int k = 0; k < 64; ++k) {
        float a0 = As[(i0 + 0) * MST + k];
        float a1 = As[(i0 + 1) * MST + k];
        float a2 = As[(i0 + 2) * MST + k];
        float a3 = As[(i0 + 3) * MST + k];
        float b0 = Bs[(j0 + 0) * MST + k];
        float b1 = Bs[(j0 + 1) * MST + k];
        float b2 = Bs[(j0 + 2) * MST + k];
        float b3 = Bs[(j0 + 3) * MST + k];
        acc[0][0] = fmaf(a0, b0, acc[0][0]); acc[0][1] = fmaf(a0, b1, acc[0][1]);
        acc[0][2] = fmaf(a0, b2, acc[0][2]); acc[0][3] = fmaf(a0, b3, acc[0][3]);
        acc[1][0] = fmaf(a1, b0, acc[1][0]); acc[1][1] = fmaf(a1, b1, acc[1][1]);
        acc[1][2] = fmaf(a1, b2, acc[1][2]); acc[1][3] = fmaf(a1, b3, acc[1][3]);
        acc[2][0] = fmaf(a2, b0, acc[2][0]); acc[2][1] = fmaf(a2, b1, acc[2][1]);
        acc[2][2] = fmaf(a2, b2, acc[2][2]); acc[2][3] = fmaf(a2, b3, acc[2][3]);
        acc[3][0] = fmaf(a3, b0, acc[3][0]); acc[3][1] = fmaf(a3, b1, acc[3][1]);
        acc[3][2] = fmaf(a3, b2, acc[3][2]); acc[3][3] = fmaf(a3, b3, acc[3][3]);
    }
    #pragma unroll
    for (int r = 0; r < 4; ++r) {
        int gi = ib + i0 + r;
        uchar4 m;
        m.x = (acc[r][0] != 0.f || gi == jb + j0 + 0) ? 1 : 0;
        m.y = (acc[r][1] != 0.f || gi == jb + j0 + 1) ? 1 : 0;
        m.z = (acc[r][2] != 0.f || gi == jb + j0 + 2) ? 1 : 0;
        m.w = (acc[r][3] != 0.f || gi == jb + j0 + 3) ? 1 : 0;
        *(uchar4*)&mask[gi * NN + jb + j0] = m;
    }
}

// --- Kernel 2: dual GEMM + alE tail --------------------------------------
// xl = A@Wl, xr = A@Wr; alE[r][h] = 0.6*log2(e)*sum_p att[h,p]*xl[r,h,p]
__global__ __launch_bounds__(256) void k_gemm2(const float* __restrict__ A,
                                               const float* __restrict__ Wl,
                                               const float* __restrict__ Wr,
                                               const float* __restrict__ att,
                                               float* __restrict__ xl,
                                               float* __restrict__ xr,
                                               float* __restrict__ alE) {
    __shared__ float wl[64 * 64];
    __shared__ float wr[64 * 64];
    int tid = threadIdx.x;
    for (int t = tid; t < 4096; t += 256) { wl[t] = Wl[t]; wr[t] = Wr[t]; }
    __syncthreads();
    int r = blockIdx.x * 4 + (tid >> 6);
    int c = tid & 63;
    float av = att[c];
    const float* arow = A + r * 64;
    float accl = 0.f, accr = 0.f;
    #pragma unroll
    for (int p = 0; p < 64; ++p) {
        float a = arow[p];
        accl = fmaf(a, wl[p * 64 + c], accl);
        accr = fmaf(a, wr[p * 64 + c], accr);
    }
    xl[r * 64 + c] = accl;
    xr[r * 64 + c] = accr;
    float t = dpp_rowsum16(accl * av);
    if ((c & 15) == 15) alE[(r << 2) | (c >> 4)] = 0.6f * LOG2E * t;
}

// --- Kernel 3: fused flash GATv2, async-LDS xv pipeline ------------------
// FOUR i-rows per block (grid 512 = 2 blocks/CU). Round-5 post-mortem: at
// ~29us/launch vs ~6.5us VALU floor the kernel is bound by the per-s xv
// load->use chain (L2 ~250cy x16, 2 waves/SIMD). Fix: wave-private
// double-buffered LDS staging via global_load_lds (async, vmcnt-counted,
// NEVER drained to 0 in-loop), and the wave's alE slice staged once at
// init (transposed so the in-loop broadcast read is 2-way = free). Steady
// state has ZERO vmem->vgpr deps: 4x gload_lds(s+1), s_waitcnt vmcnt(4),
// 5x conflict-free ds_read_b128, then pure VALU. Wave-private buffers =>
// no barriers needed. Math identical to round 5.
// Per-row state remains SEPARATE NAMED 16-float arrays (SROA rule,
// rounds 2-3: 256B aggregates go to scratch; 64B named arrays promote).
template <bool RELU>
__global__ __launch_bounds__(256, 2) void k_attn(
    const float* __restrict__ xl, const float* __restrict__ xr,
    const float* __restrict__ att, const float* __restrict__ alE,
    const float* __restrict__ bias, const unsigned char* __restrict__ mask,
    float* __restrict__ out)
{
    __shared__ __align__(16) float XBUF[4][2][1024];  // [wave][dbuf][16rows x 64f]
    __shared__ __align__(16) float ABUF[4][1024];     // [wave][256rows x 4f, transposed]
    __shared__ float Opart[4][4][4][64];              // [ii][wave][jlgrp][p]
    __shared__ float Lpart[4][4][4][NHEAD];

    int tid = threadIdx.x;
    int wave = tid >> 6, lane = tid & 63;
    int h = lane & 3, jl = lane >> 2;
    int b = blockIdx.x >> 8;
    int i0 = (blockIdx.x & 255) << 2;
    int j0 = (wave << 8) + (jl << 4);

    const float* xlb = xl + (b << 16);

    // ---- issue-order matters: plain init loads first, then async stages,
    // then VALU init work overlapping the stages' flight time.

    // permuted persistent fragments: slot q*4+r  <->  p = q*16 + 4h + r
    float at[16], xr0f[16], xr1f[16], xr2f[16], xr3f[16];
    {
        const float* ap = att + (h << 2);
        const float* r0 = xr + (((b << 10) + i0) << 6) + (h << 2);
        const float* r1 = r0 + 64;
        const float* r2 = r0 + 128;
        const float* r3 = r0 + 192;
        #pragma unroll
        for (int q = 0; q < 4; ++q) {
            *(float4*)&at[q << 2]   = *(const float4*)(ap + (q << 4));
            *(float4*)&xr0f[q << 2] = *(const float4*)(r0 + (q << 4));
            *(float4*)&xr1f[q << 2] = *(const float4*)(r1 + (q << 4));
            *(float4*)&xr2f[q << 2] = *(const float4*)(r2 + (q << 4));
            *(float4*)&xr3f[q << 2] = *(const float4*)(r3 + (q << 4));
        }
        #pragma unroll
        for (int p = 0; p < 16; ++p) at[p] *= 0.4f * LOG2E;
    }
    // mask words (loaded now, packed later while stages fly)
    unsigned w0q[4], w1q[4], w2q[4], w3q[4];
    {
        const unsigned* m0p = (const unsigned*)(mask + (i0 + 0) * NN + j0);
        const unsigned* m1p = (const unsigned*)(mask + (i0 + 1) * NN + j0);
        const unsigned* m2p = (const unsigned*)(mask + (i0 + 2) * NN + j0);
        const unsigned* m3p = (const unsigned*)(mask + (i0 + 3) * NN + j0);
        #pragma unroll
        for (int q = 0; q < 4; ++q) { w0q[q] = m0p[q]; w1q[q] = m1p[q]; w2q[q] = m2p[q]; w3q[q] = m3p[q]; }
    }

    // ---- async stages: alE slice (transposed) + xv step 0
    {
        const float* ga = alE + (b << 12) + (wave << 10);  // wave's 256 rows x 4f
        float* da = &ABUF[wave][0];
        #pragma unroll
        for (int t = 0; t < 4; ++t) {
            int u = (t << 6) + lane;                 // LDS slot u (16B each)
            int r = ((u & 15) << 4) | (u >> 4);      // transposed: slot u <- row r
            gload_lds16(ga + (r << 2), da + (t << 8));
        }
    }
    {
        float* d0 = &XBUF[wave][0][0];
        const float* g0 = xlb + (((wave << 8) + (jl << 4) + 0) << 6) + (h << 2);
        gload_lds16(g0,      d0);
        gload_lds16(g0 + 16, d0 + 256);
        gload_lds16(g0 + 32, d0 + 512);
        gload_lds16(g0 + 48, d0 + 768);
    }

    // ---- VALU init under the stages' flight time
    float ar0q[4], ar1q[4], ar2q[4], ar3q[4];
    #pragma unroll
    for (int q = 0; q < 4; ++q) {
        float p0 = 0.f, p1 = 0.f, p2 = 0.f, p3 = 0.f;
        #pragma unroll
        for (int r = 0; r < 4; ++r) {
            float a = at[(q << 2) + r];
            p0 = fmaf(a, xr0f[(q << 2) + r], p0);
            p1 = fmaf(a, xr1f[(q << 2) + r], p1);
            p2 = fmaf(a, xr2f[(q << 2) + r], p2);
            p3 = fmaf(a, xr3f[(q << 2) + r], p3);
        }
        ar0q[q] = 1.5f * quad_sum4(p0);
        ar1q[q] = 1.5f * quad_sum4(p1);
        ar2q[q] = 1.5f * quad_sum4(p2);
        ar3q[q] = 1.5f * quad_sum4(p3);
    }
    unsigned mb0 = 0, mb1 = 0, mb2 = 0, mb3 = 0;
    #pragma unroll
    for (int q = 0; q < 4; ++q) {
        unsigned w0 = w0q[q], w1 = w1q[q], w2 = w2q[q], w3 = w3q[q];
        mb0 |= ((((w0 >> 0) & 1) | ((w0 >> 7) & 2) | ((w0 >> 14) & 4) | ((w0 >> 21) & 8)) << (q << 2));
        mb1 |= ((((w1 >> 0) & 1) | ((w1 >> 7) & 2) | ((w1 >> 14) & 4) | ((w1 >> 21) & 8)) << (q << 2));
        mb2 |= ((((w2 >> 0) & 1) | ((w2 >> 7) & 2) | ((w2 >> 14) & 4) | ((w2 >> 21) & 8)) << (q << 2));
        mb3 |= ((((w3 >> 0) & 1) | ((w3 >> 7) & 2) | ((w3 >> 14) & 4) | ((w3 >> 21) & 8)) << (q << 2));
    }

    float O0[16], O1[16], O2[16], O3[16];
    float l0q[4] = {}, l1q[4] = {}, l2q[4] = {}, l3q[4] = {};
    #pragma unroll
    for (int p = 0; p < 16; ++p) { O0[p] = 0.f; O1[p] = 0.f; O2[p] = 0.f; O3[p] = 0.f; }

    #pragma unroll 2
    for (int s = 0; s < 16; ++s) {
        // stage s+1 (s=15 stages a dead tile: rows stay inside the workspace;
        // keeps the vmcnt count uniform)
        {
            float* dn = &XBUF[wave][(s + 1) & 1][0];
            const float* gn = xlb + (((wave << 8) + (jl << 4) + (s + 1)) << 6) + (h << 2);
            gload_lds16(gn,      dn);
            gload_lds16(gn + 16, dn + 256);
            gload_lds16(gn + 32, dn + 512);
            gload_lds16(gn + 48, dn + 768);
        }
        // wait: everything older than the 4 just-issued loads (i.e. stage(s)
        // and, at s=0, the alE stage) is complete. Never drains to 0.
        asm volatile("s_waitcnt vmcnt(4)" ::: "memory");

        const float* xb = &XBUF[wave][s & 1][0];
        float xv[16];
        *(float4*)&xv[0]  = *(const float4*)(xb + (lane << 2));
        *(float4*)&xv[4]  = *(const float4*)(xb + 256 + (lane << 2));
        *(float4*)&xv[8]  = *(const float4*)(xb + 512 + (lane << 2));
        *(float4*)&xv[12] = *(const float4*)(xb + 768 + (lane << 2));
        float alr[4];
        *(float4*)alr = *(const float4*)(&ABUF[wave][(s << 6) + (jl << 2)]);

        bool m0 = (mb0 >> s) & 1, m1 = (mb1 >> s) & 1;
        bool m2 = (mb2 >> s) & 1, m3 = (mb3 >> s) & 1;

        #pragma unroll
        for (int q = 0; q < 4; ++q) {
            float p0 = 0.f, p1 = 0.f, p2 = 0.f, p3 = 0.f;
            #pragma unroll
            for (int r = 0; r < 4; ++r) {
                float xvv = xv[(q << 2) + r];
                float a = at[(q << 2) + r];
                p0 = fmaf(a, __builtin_fabsf(xr0f[(q << 2) + r] + xvv), p0);
                p1 = fmaf(a, __builtin_fabsf(xr1f[(q << 2) + r] + xvv), p1);
                p2 = fmaf(a, __builtin_fabsf(xr2f[(q << 2) + r] + xvv), p2);
                p3 = fmaf(a, __builtin_fabsf(xr3f[(q << 2) + r] + xvv), p3);
            }
            float e0 = quad_sum4(p0) + (ar0q[q] + alr[q]);
            float e1 = quad_sum4(p1) + (ar1q[q] + alr[q]);
            float e2 = quad_sum4(p2) + (ar2q[q] + alr[q]);
            float e3 = quad_sum4(p3) + (ar3q[q] + alr[q]);
            float pe0 = m0 ? __builtin_amdgcn_exp2f(e0) : 0.f;
            float pe1 = m1 ? __builtin_amdgcn_exp2f(e1) : 0.f;
            float pe2 = m2 ? __builtin_amdgcn_exp2f(e2) : 0.f;
            float pe3 = m3 ? __builtin_amdgcn_exp2f(e3) : 0.f;
            l0q[q] += pe0; l1q[q] += pe1; l2q[q] += pe2; l3q[q] += pe3;
            #pragma unroll
            for (int r = 0; r < 4; ++r) {
                float xvv = xv[(q << 2) + r];
                O0[(q << 2) + r] = fmaf(pe0, xvv, O0[(q << 2) + r]);
                O1[(q << 2) + r] = fmaf(pe1, xvv, O1[(q << 2) + r]);
                O2[(q << 2) + r] = fmaf(pe2, xvv, O2[(q << 2) + r]);
                O3[(q << 2) + r] = fmaf(pe3, xvv, O3[(q << 2) + r]);
            }
        }
    }

    // reduce over the 4 jl's within each 16-lane DPP row (stride-4 lanes)
    #pragma unroll
    for (int p = 0; p < 16; ++p) {
        O0[p] += dpp_mov<0x114>(O0[p]);  O0[p] += dpp_mov<0x118>(O0[p]);
        O1[p] += dpp_mov<0x114>(O1[p]);  O1[p] += dpp_mov<0x118>(O1[p]);
        O2[p] += dpp_mov<0x114>(O2[p]);  O2[p] += dpp_mov<0x118>(O2[p]);
        O3[p] += dpp_mov<0x114>(O3[p]);  O3[p] += dpp_mov<0x118>(O3[p]);
    }
    #pragma unroll
    for (int q = 0; q < 4; ++q) {
        l0q[q] += dpp_mov<0x114>(l0q[q]);  l0q[q] += dpp_mov<0x118>(l0q[q]);
        l1q[q] += dpp_mov<0x114>(l1q[q]);  l1q[q] += dpp_mov<0x118>(l1q[q]);
        l2q[q] += dpp_mov<0x114>(l2q[q]);  l2q[q] += dpp_mov<0x118>(l2q[q]);
        l3q[q] += dpp_mov<0x114>(l3q[q]);  l3q[q] += dpp_mov<0x118>(l3q[q]);
    }

    if ((lane & 15) >= 12) {             // lanes 12..15 of each DPP row
        int k = lane >> 4;               // jl-group
        #pragma unroll
        for (int q = 0; q < 4; ++q) {
            *(float4*)&Opart[0][wave][k][(q << 4) + (h << 2)] = *(const float4*)&O0[q << 2];
            *(float4*)&Opart[1][wave][k][(q << 4) + (h << 2)] = *(const float4*)&O1[q << 2];
            *(float4*)&Opart[2][wave][k][(q << 4) + (h << 2)] = *(const float4*)&O2[q << 2];
            *(float4*)&Opart[3][wave][k][(q << 4) + (h << 2)] = *(const float4*)&O3[q << 2];
        }
        if (h == 0) {
            #pragma unroll
            for (int q = 0; q < 4; ++q) {
                Lpart[0][wave][k][q] = l0q[q];
                Lpart[1][wave][k][q] = l1q[q];
                Lpart[2][wave][k][q] = l2q[q];
                Lpart[3][wave][k][q] = l3q[q];
            }
        }
    }
    __syncthreads();

    {
        int ii = tid >> 6, c = tid & 63;
        float o = 0.f, l = 0.f;
        #pragma unroll
        for (int w = 0; w < 4; ++w)
            #pragma unroll
            for (int k = 0; k < 4; ++k) {
                o += Opart[ii][w][k][c];
                l += Lpart[ii][w][k][c >> 4];
            }
        float res = o / l + bias[c];
        if (RELU) res = fmaxf(res, 0.f);
        out[((b << 10) + i0 + ii) * D + c] = res;
    }
}

extern "C" void kernel_launch(void* const* d_in, const int* in_sizes, int n_in,
                              void* d_out, int out_size, void* d_ws, size_t ws_size,
                              hipStream_t stream) {
    const float* x    = (const float*)d_in[0];
    const float* emb  = (const float*)d_in[1];
    const float* Wl1  = (const float*)d_in[2];
    const float* Wr1  = (const float*)d_in[3];
    const float* att1 = (const float*)d_in[4];
    const float* b1   = (const float*)d_in[5];
    const float* Wl2  = (const float*)d_in[6];
    const float* Wr2  = (const float*)d_in[7];
    const float* att2 = (const float*)d_in[8];
    const float* b2   = (const float*)d_in[9];
    float* out = (float*)d_out;

    unsigned char* mask = (unsigned char*)d_ws;                 // 1MB
    float* xl = (float*)(mask + NN * NN);                       // 512KB
    float* xr = xl + BB * NN * D;                               // 512KB
    float* hbuf = xr + BB * NN * D;                             // 512KB
    float* alE = hbuf + BB * NN * D;                            // 32KB

    k_mask<<<256, 256, 0, stream>>>(emb, mask);

    k_gemm2<<<BB * NN / 4, 256, 0, stream>>>(x, Wl1, Wr1, att1, xl, xr, alE);
    k_attn<true><<<BB * NN / 4, 256, 0, stream>>>(xl, xr, att1, alE, b1, mask, hbuf);

    k_gemm2<<<BB * NN / 4, 256, 0, stream>>>(hbuf, Wl2, Wr2, att2, xl, xr, alE);
    k_attn<false><<<BB * NN / 4, 256, 0, stream>>>(xl, xr, att2, alE, b2, mask, out);
}

// Round 8
// 130.379 us; speedup vs baseline: 1.0451x; 1.0451x over previous
//
#include <hip/hip_runtime.h>
#include <math.h>

#define NN 1024
#define BB 2
#define D 64
#define NHEAD 4
#define LOG2E 1.4426950408889634f
#define MST 65

template <int CTRL>
__device__ __forceinline__ float dpp_mov(float x) {
    int xi = __builtin_bit_cast(int, x);
    int r = __builtin_amdgcn_update_dpp(0, xi, CTRL, 0xF, 0xF, true);
    return __builtin_bit_cast(float, r);
}

// 16-lane row sum; valid in lane 15 of each row of 16.
__device__ __forceinline__ float dpp_rowsum16(float t) {
    t += dpp_mov<0x111>(t);
    t += dpp_mov<0x112>(t);
    t += dpp_mov<0x114>(t);
    t += dpp_mov<0x118>(t);
    return t;
}

// --- Kernel 1: merged {adjacency mask GEMM} + {layer-1 dual GEMM} --------
// Independent inputs -> one dispatch, block-range split (saves a launch
// boundary). LDS unioned: mask needs 2x64xMST=33.3KB, gemm 32KB.
// mask: norms positive & finite, so (ne_i.ne_j != 0) <=> (emb_i.emb_j != 0).
// gemm: xl = A@Wl (stored PERMUTED, see k_attn), xr = A@Wr,
//       alE[r][h] = 0.6*log2(e)*sum_p att[h,p]*xl[r,h,p].
__global__ __launch_bounds__(256) void k_mask_gemm(
    const float* __restrict__ emb, unsigned char* __restrict__ mask,
    const float* __restrict__ A, const float* __restrict__ Wl,
    const float* __restrict__ Wr, const float* __restrict__ att,
    float* __restrict__ xl, float* __restrict__ xr, float* __restrict__ alE)
{
    __shared__ float SH[64 * MST * 2];
    int tid = threadIdx.x;
    if (blockIdx.x < 256) {
        float* As = SH;
        float* Bs = SH + 64 * MST;
        int ib = (blockIdx.x & 15) << 6;
        int jb = (blockIdx.x >> 4) << 6;

        #pragma unroll
        for (int r = 0; r < 4; ++r) {
            int q = tid + (r << 8);
            int row = q >> 4, c4 = (q & 15) << 2;
            float4 a = *(const float4*)&emb[(ib + row) * D + c4];
            float4 b = *(const float4*)&emb[(jb + row) * D + c4];
            As[row * MST + c4 + 0] = a.x; As[row * MST + c4 + 1] = a.y;
            As[row * MST + c4 + 2] = a.z; As[row * MST + c4 + 3] = a.w;
            Bs[row * MST + c4 + 0] = b.x; Bs[row * MST + c4 + 1] = b.y;
            Bs[row * MST + c4 + 2] = b.z; Bs[row * MST + c4 + 3] = b.w;
        }
        __syncthreads();

        int i0 = (tid >> 4) << 2;
        int j0 = (tid & 15) << 2;
        float acc[4][4] = {};
        #pragma unroll 8
        for (int k = 0; k < 64; ++k) {
            float a0 = As[(i0 + 0) * MST + k];
            float a1 = As[(i0 + 1) * MST + k];
            float a2 = As[(i0 + 2) * MST + k];
            float a3 = As[(i0 + 3) * MST + k];
            float b0 = Bs[(j0 + 0) * MST + k];
            float b1 = Bs[(j0 + 1) * MST + k];
            float b2 = Bs[(j0 + 2) * MST + k];
            float b3 = Bs[(j0 + 3) * MST + k];
            acc[0][0] = fmaf(a0, b0, acc[0][0]); acc[0][1] = fmaf(a0, b1, acc[0][1]);
            acc[0][2] = fmaf(a0, b2, acc[0][2]); acc[0][3] = fmaf(a0, b3, acc[0][3]);
            acc[1][0] = fmaf(a1, b0, acc[1][0]); acc[1][1] = fmaf(a1, b1, acc[1][1]);
            acc[1][2] = fmaf(a1, b2, acc[1][2]); acc[1][3] = fmaf(a1, b3, acc[1][3]);
            acc[2][0] = fmaf(a2, b0, acc[2][0]); acc[2][1] = fmaf(a2, b1, acc[2][1]);
            acc[2][2] = fmaf(a2, b2, acc[2][2]); acc[2][3] = fmaf(a2, b3, acc[2][3]);
            acc[3][0] = fmaf(a3, b0, acc[3][0]); acc[3][1] = fmaf(a3, b1, acc[3][1]);
            acc[3][2] = fmaf(a3, b2, acc[3][2]); acc[3][3] = fmaf(a3, b3, acc[3][3]);
        }
        #pragma unroll
        for (int r = 0; r < 4; ++r) {
            int gi = ib + i0 + r;
            uchar4 m;
            m.x = (acc[r][0] != 0.f || gi == jb + j0 + 0) ? 1 : 0;
            m.y = (acc[r][1] != 0.f || gi == jb + j0 + 1) ? 1 : 0;
            m.z = (acc[r][2] != 0.f || gi == jb + j0 + 2) ? 1 : 0;
            m.w = (acc[r][3] != 0.f || gi == jb + j0 + 3) ? 1 : 0;
            *(uchar4*)&mask[gi * NN + jb + j0] = m;
        }
    } else {
        float* wl = SH;
        float* wr = SH + 4096;
        for (int t = tid; t < 4096; t += 256) { wl[t] = Wl[t]; wr[t] = Wr[t]; }
        __syncthreads();
        int r = (blockIdx.x - 256) * 4 + (tid >> 6);
        int c = tid & 63;
        float av = att[c];
        const float* arow = A + r * 64;
        float accl = 0.f, accr = 0.f;
        #pragma unroll
        for (int p = 0; p < 64; ++p) {
            float a = arow[p];
            accl = fmaf(a, wl[p * 64 + c], accl);
            accr = fmaf(a, wr[p * 64 + c], accr);
        }
        // permuted xl store: logical col c = h*16 + c4*4 + r  ->  c4*16 + h*4 + r
        int cp = (((c >> 2) & 3) << 4) | ((c >> 4) << 2) | (c & 3);
        xl[r * 64 + cp] = accl;
        xr[r * 64 + c] = accr;
        float t = dpp_rowsum16(accl * av);
        if ((c & 15) == 15) alE[(r << 2) | (c >> 4)] = 0.6f * LOG2E * t;
    }
}

// --- Kernel 2: dual GEMM + alE tail (layer 2 standalone) -----------------
__global__ __launch_bounds__(256) void k_gemm2(const float* __restrict__ A,
                                               const float* __restrict__ Wl,
                                               const float* __restrict__ Wr,
                                               const float* __restrict__ att,
                                               float* __restrict__ xl,
                                               float* __restrict__ xr,
                                               float* __restrict__ alE) {
    __shared__ float wl[64 * 64];
    __shared__ float wr[64 * 64];
    int tid = threadIdx.x;
    for (int t = tid; t < 4096; t += 256) { wl[t] = Wl[t]; wr[t] = Wr[t]; }
    __syncthreads();
    int r = blockIdx.x * 4 + (tid >> 6);
    int c = tid & 63;
    float av = att[c];
    const float* arow = A + r * 64;
    float accl = 0.f, accr = 0.f;
    #pragma unroll
    for (int p = 0; p < 64; ++p) {
        float a = arow[p];
        accl = fmaf(a, wl[p * 64 + c], accl);
        accr = fmaf(a, wr[p * 64 + c], accr);
    }
    int cp = (((c >> 2) & 3) << 4) | ((c >> 4) << 2) | (c & 3);
    xl[r * 64 + cp] = accl;
    xr[r * 64 + c] = accr;
    float t = dpp_rowsum16(accl * av);
    if ((c & 15) == 15) alE[(r << 2) | (c >> 4)] = 0.6f * LOG2E * t;
}

// --- Kernel 3: fused flash GATv2, head-per-lane --------------------------
// FOUR i-rows per block (grid 512 = 2 blocks/CU), direct loads (round-6
// ablation: async-LDS pipeline was neutral -> latency already hidden by
// unroll-2; instruction count is the lever). HEAD-PER-LANE: xl is stored
// with the (head, chunk) 4x4 grid transposed, so the SAME load addresses
// as round 5 now deliver each lane its OWN head's 16 elements. The score
// dot is fully in-lane (4 chains of 4 + tree) -> the 64 DPP+add quad-sum
// instructions per s-iter vanish and exp/cndmask/e-adds drop 4x
// (341 -> ~229 instr/s-iter). FP-identical to round 5: same chain groups
// (p div 4), same add tree, commutativity covers lane-order differences.
// lane = 4*jl + h; quad (jl) shares row j = wave*256 + jl*16 + s; lane
// owns head h entirely. Per-row state = SEPARATE NAMED 16-float arrays
// (SROA rule from rounds 2-3).
template <bool RELU>
__global__ __launch_bounds__(256, 2) void k_attn(
    const float* __restrict__ xlp, const float* __restrict__ xr,
    const float* __restrict__ att, const float* __restrict__ alE,
    const float* __restrict__ bias, const unsigned char* __restrict__ mask,
    float* __restrict__ out)
{
    __shared__ float Opart[4][4][4][64];   // [ii][wave][jlgrp][p]
    __shared__ float Lpart[4][4][4][NHEAD];

    int tid = threadIdx.x;
    int wave = tid >> 6, lane = tid & 63;
    int h = lane & 3, jl = lane >> 2;
    int b = blockIdx.x >> 8;
    int i0 = (blockIdx.x & 255) << 2;
    int j0 = (wave << 8) + (jl << 4);

    const float* xlb = xlp + (b << 16);

    // natural head-h slices: at[p] = att[h][p], xr?f[p] = xr[row][h*16+p]
    float at[16], xr0f[16], xr1f[16], xr2f[16], xr3f[16];
    {
        const float* ap = att + (h << 4);
        const float* r0 = xr + (((b << 10) + i0) << 6) + (h << 4);
        const float* r1 = r0 + 64;
        const float* r2 = r0 + 128;
        const float* r3 = r0 + 192;
        #pragma unroll
        for (int c = 0; c < 4; ++c) {
            *(float4*)&at[c << 2]   = *(const float4*)(ap + (c << 2));
            *(float4*)&xr0f[c << 2] = *(const float4*)(r0 + (c << 2));
            *(float4*)&xr1f[c << 2] = *(const float4*)(r1 + (c << 2));
            *(float4*)&xr2f[c << 2] = *(const float4*)(r2 + (c << 2));
            *(float4*)&xr3f[c << 2] = *(const float4*)(r3 + (c << 2));
        }
        #pragma unroll
        for (int p = 0; p < 16; ++p) at[p] *= 0.4f * LOG2E;
    }
    // arE per row, fully in-lane (same chain groups + tree as the old
    // butterfly -> bit-identical)
    float ar0, ar1, ar2, ar3;
    {
        float s0[4], s1[4], s2[4], s3[4];
        #pragma unroll
        for (int c = 0; c < 4; ++c) {
            float t0 = 0.f, t1 = 0.f, t2 = 0.f, t3 = 0.f;
            #pragma unroll
            for (int r = 0; r < 4; ++r) {
                int p = (c << 2) + r;
                float a = at[p];
                t0 = fmaf(a, xr0f[p], t0);
                t1 = fmaf(a, xr1f[p], t1);
                t2 = fmaf(a, xr2f[p], t2);
                t3 = fmaf(a, xr3f[p], t3);
            }
            s0[c] = t0; s1[c] = t1; s2[c] = t2; s3[c] = t3;
        }
        ar0 = 1.5f * ((s0[0] + s0[1]) + (s0[2] + s0[3]));
        ar1 = 1.5f * ((s1[0] + s1[1]) + (s1[2] + s1[3]));
        ar2 = 1.5f * ((s2[0] + s2[1]) + (s2[2] + s2[3]));
        ar3 = 1.5f * ((s3[0] + s3[1]) + (s3[2] + s3[3]));
    }

    // pack this lane's 16 mask bytes into 16 bits, rows i0..i0+3
    unsigned mb0 = 0, mb1 = 0, mb2 = 0, mb3 = 0;
    {
        const unsigned* m0p = (const unsigned*)(mask + (i0 + 0) * NN + j0);
        const unsigned* m1p = (const unsigned*)(mask + (i0 + 1) * NN + j0);
        const unsigned* m2p = (const unsigned*)(mask + (i0 + 2) * NN + j0);
        const unsigned* m3p = (const unsigned*)(mask + (i0 + 3) * NN + j0);
        #pragma unroll
        for (int q = 0; q < 4; ++q) {
            unsigned w0 = m0p[q], w1 = m1p[q], w2 = m2p[q], w3 = m3p[q];
            mb0 |= ((((w0 >> 0) & 1) | ((w0 >> 7) & 2) | ((w0 >> 14) & 4) | ((w0 >> 21) & 8)) << (q << 2));
            mb1 |= ((((w1 >> 0) & 1) | ((w1 >> 7) & 2) | ((w1 >> 14) & 4) | ((w1 >> 21) & 8)) << (q << 2));
            mb2 |= ((((w2 >> 0) & 1) | ((w2 >> 7) & 2) | ((w2 >> 14) & 4) | ((w2 >> 21) & 8)) << (q << 2));
            mb3 |= ((((w3 >> 0) & 1) | ((w3 >> 7) & 2) | ((w3 >> 14) & 4) | ((w3 >> 21) & 8)) << (q << 2));
        }
    }

    float O0[16], O1[16], O2[16], O3[16];
    float lq0 = 0.f, lq1 = 0.f, lq2 = 0.f, lq3 = 0.f;
    #pragma unroll
    for (int p = 0; p < 16; ++p) { O0[p] = 0.f; O1[p] = 0.f; O2[p] = 0.f; O3[p] = 0.f; }

    // permuted xl: same addresses as round 5; bytes [c*64 + h*16) of row j
    // hold head h elems {c*4..c*4+4}.
    const float* xrow = xlb + (j0 << 6) + (h << 2);
    const float* alp  = alE + (b << 12) + (j0 << 2) + h;

    #pragma unroll 2
    for (int s = 0; s < 16; ++s) {
        const float* rp = xrow + (s << 6);
        float xv[16];
        *(float4*)&xv[0]  = *(const float4*)(rp);
        *(float4*)&xv[4]  = *(const float4*)(rp + 16);
        *(float4*)&xv[8]  = *(const float4*)(rp + 32);
        *(float4*)&xv[12] = *(const float4*)(rp + 48);
        float alr = alp[s << 2];
        bool m0 = (mb0 >> s) & 1, m1 = (mb1 >> s) & 1;
        bool m2 = (mb2 >> s) & 1, m3 = (mb3 >> s) & 1;

        float s0[4], s1[4], s2[4], s3[4];
        #pragma unroll
        for (int c = 0; c < 4; ++c) {
            float t0 = 0.f, t1 = 0.f, t2 = 0.f, t3 = 0.f;
            #pragma unroll
            for (int r = 0; r < 4; ++r) {
                int p = (c << 2) + r;
                float a = at[p], xvv = xv[p];
                t0 = fmaf(a, __builtin_fabsf(xr0f[p] + xvv), t0);
                t1 = fmaf(a, __builtin_fabsf(xr1f[p] + xvv), t1);
                t2 = fmaf(a, __builtin_fabsf(xr2f[p] + xvv), t2);
                t3 = fmaf(a, __builtin_fabsf(xr3f[p] + xvv), t3);
            }
            s0[c] = t0; s1[c] = t1; s2[c] = t2; s3[c] = t3;
        }
        float e0 = ((s0[0] + s0[1]) + (s0[2] + s0[3])) + (ar0 + alr);
        float e1 = ((s1[0] + s1[1]) + (s1[2] + s1[3])) + (ar1 + alr);
        float e2 = ((s2[0] + s2[1]) + (s2[2] + s2[3])) + (ar2 + alr);
        float e3 = ((s3[0] + s3[1]) + (s3[2] + s3[3])) + (ar3 + alr);
        float pe0 = m0 ? __builtin_amdgcn_exp2f(e0) : 0.f;
        float pe1 = m1 ? __builtin_amdgcn_exp2f(e1) : 0.f;
        float pe2 = m2 ? __builtin_amdgcn_exp2f(e2) : 0.f;
        float pe3 = m3 ? __builtin_amdgcn_exp2f(e3) : 0.f;
        lq0 += pe0; lq1 += pe1; lq2 += pe2; lq3 += pe3;
        #pragma unroll
        for (int p = 0; p < 16; ++p) {
            float xvv = xv[p];
            O0[p] = fmaf(pe0, xvv, O0[p]);
            O1[p] = fmaf(pe1, xvv, O1[p]);
            O2[p] = fmaf(pe2, xvv, O2[p]);
            O3[p] = fmaf(pe3, xvv, O3[p]);
        }
    }

    // reduce over the 4 jl's within each 16-lane DPP row (stride-4 lanes)
    #pragma unroll
    for (int p = 0; p < 16; ++p) {
        O0[p] += dpp_mov<0x114>(O0[p]);  O0[p] += dpp_mov<0x118>(O0[p]);
        O1[p] += dpp_mov<0x114>(O1[p]);  O1[p] += dpp_mov<0x118>(O1[p]);
        O2[p] += dpp_mov<0x114>(O2[p]);  O2[p] += dpp_mov<0x118>(O2[p]);
        O3[p] += dpp_mov<0x114>(O3[p]);  O3[p] += dpp_mov<0x118>(O3[p]);
    }
    lq0 += dpp_mov<0x114>(lq0);  lq0 += dpp_mov<0x118>(lq0);
    lq1 += dpp_mov<0x114>(lq1);  lq1 += dpp_mov<0x118>(lq1);
    lq2 += dpp_mov<0x114>(lq2);  lq2 += dpp_mov<0x118>(lq2);
    lq3 += dpp_mov<0x114>(lq3);  lq3 += dpp_mov<0x118>(lq3);

    if ((lane & 15) >= 12) {             // lanes 12..15 of each DPP row
        int k = lane >> 4;               // jl-group
        #pragma unroll
        for (int c = 0; c < 4; ++c) {
            *(float4*)&Opart[0][wave][k][(h << 4) + (c << 2)] = *(const float4*)&O0[c << 2];
            *(float4*)&Opart[1][wave][k][(h << 4) + (c << 2)] = *(const float4*)&O1[c << 2];
            *(float4*)&Opart[2][wave][k][(h << 4) + (c << 2)] = *(const float4*)&O2[c << 2];
            *(float4*)&Opart[3][wave][k][(h << 4) + (c << 2)] = *(const float4*)&O3[c << 2];
        }
        Lpart[0][wave][k][h] = lq0;
        Lpart[1][wave][k][h] = lq1;
        Lpart[2][wave][k][h] = lq2;
        Lpart[3][wave][k][h] = lq3;
    }
    __syncthreads();

    {
        int ii = tid >> 6, c = tid & 63;
        float o = 0.f, l = 0.f;
        #pragma unroll
        for (int w = 0; w < 4; ++w)
            #pragma unroll
            for (int k = 0; k < 4; ++k) {
                o += Opart[ii][w][k][c];
                l += Lpart[ii][w][k][c >> 4];
            }
        float res = o / l + bias[c];
        if (RELU) res = fmaxf(res, 0.f);
        out[((b << 10) + i0 + ii) * D + c] = res;
    }
}

extern "C" void kernel_launch(void* const* d_in, const int* in_sizes, int n_in,
                              void* d_out, int out_size, void* d_ws, size_t ws_size,
                              hipStream_t stream) {
    const float* x    = (const float*)d_in[0];
    const float* emb  = (const float*)d_in[1];
    const float* Wl1  = (const float*)d_in[2];
    const float* Wr1  = (const float*)d_in[3];
    const float* att1 = (const float*)d_in[4];
    const float* b1   = (const float*)d_in[5];
    const float* Wl2  = (const float*)d_in[6];
    const float* Wr2  = (const float*)d_in[7];
    const float* att2 = (const float*)d_in[8];
    const float* b2   = (const float*)d_in[9];
    float* out = (float*)d_out;

    unsigned char* mask = (unsigned char*)d_ws;                 // 1MB
    float* xl = (float*)(mask + NN * NN);                       // 512KB (permuted)
    float* xr = xl + BB * NN * D;                               // 512KB
    float* hbuf = xr + BB * NN * D;                             // 512KB
    float* alE = hbuf + BB * NN * D;                            // 32KB

    k_mask_gemm<<<256 + BB * NN / 4, 256, 0, stream>>>(emb, mask, x, Wl1, Wr1, att1, xl, xr, alE);
    k_attn<true><<<BB * NN / 4, 256, 0, stream>>>(xl, xr, att1, alE, b1, mask, hbuf);

    k_gemm2<<<BB * NN / 4, 256, 0, stream>>>(hbuf, Wl2, Wr2, att2, xl, xr, alE);
    k_attn<false><<<BB * NN / 4, 256, 0, stream>>>(xl, xr, att2, alE, b2, mask, out);
}

// Round 10
// 128.204 us; speedup vs baseline: 1.0628x; 1.0170x over previous
//
#include <hip/hip_runtime.h>
#include <math.h>

#define NN 1024
#define BB 2
#define D 64
#define NHEAD 4
#define LOG2E 1.4426950408889634f
#define MST 65

template <int CTRL>
__device__ __forceinline__ float dpp_mov(float x) {
    int xi = __builtin_bit_cast(int, x);
    int r = __builtin_amdgcn_update_dpp(0, xi, CTRL, 0xF, 0xF, true);
    return __builtin_bit_cast(float, r);
}

// 16-lane row sum; valid in lane 15 of each row of 16.
__device__ __forceinline__ float dpp_rowsum16(float t) {
    t += dpp_mov<0x111>(t);
    t += dpp_mov<0x112>(t);
    t += dpp_mov<0x114>(t);
    t += dpp_mov<0x118>(t);
    return t;
}

// --- Kernel 1: merged {adjacency mask GEMM} + {layer-1 dual GEMM} --------
// (round-8 verbatim, verified) Independent inputs -> one dispatch.
// mask: norms positive & finite, so (ne_i.ne_j != 0) <=> (emb_i.emb_j != 0).
// gemm: xl = A@Wl (stored PERMUTED, see k_attn), xr = A@Wr,
//       alE[r][h] = 0.6*log2(e)*sum_p att[h,p]*xl[r,h,p].
__global__ __launch_bounds__(256) void k_mask_gemm(
    const float* __restrict__ emb, unsigned char* __restrict__ mask,
    const float* __restrict__ A, const float* __restrict__ Wl,
    const float* __restrict__ Wr, const float* __restrict__ att,
    float* __restrict__ xl, float* __restrict__ xr, float* __restrict__ alE)
{
    __shared__ float SH[64 * MST * 2];
    int tid = threadIdx.x;
    if (blockIdx.x < 256) {
        float* As = SH;
        float* Bs = SH + 64 * MST;
        int ib = (blockIdx.x & 15) << 6;
        int jb = (blockIdx.x >> 4) << 6;

        #pragma unroll
        for (int r = 0; r < 4; ++r) {
            int q = tid + (r << 8);
            int row = q >> 4, c4 = (q & 15) << 2;
            float4 a = *(const float4*)&emb[(ib + row) * D + c4];
            float4 b = *(const float4*)&emb[(jb + row) * D + c4];
            As[row * MST + c4 + 0] = a.x; As[row * MST + c4 + 1] = a.y;
            As[row * MST + c4 + 2] = a.z; As[row * MST + c4 + 3] = a.w;
            Bs[row * MST + c4 + 0] = b.x; Bs[row * MST + c4 + 1] = b.y;
            Bs[row * MST + c4 + 2] = b.z; Bs[row * MST + c4 + 3] = b.w;
        }
        __syncthreads();

        int i0 = (tid >> 4) << 2;
        int j0 = (tid & 15) << 2;
        float acc[4][4] = {};
        #pragma unroll 8
        for (int k = 0; k < 64; ++k) {
            float a0 = As[(i0 + 0) * MST + k];
            float a1 = As[(i0 + 1) * MST + k];
            float a2 = As[(i0 + 2) * MST + k];
            float a3 = As[(i0 + 3) * MST + k];
            float b0 = Bs[(j0 + 0) * MST + k];
            float b1 = Bs[(j0 + 1) * MST + k];
            float b2 = Bs[(j0 + 2) * MST + k];
            float b3 = Bs[(j0 + 3) * MST + k];
            acc[0][0] = fmaf(a0, b0, acc[0][0]); acc[0][1] = fmaf(a0, b1, acc[0][1]);
            acc[0][2] = fmaf(a0, b2, acc[0][2]); acc[0][3] = fmaf(a0, b3, acc[0][3]);
            acc[1][0] = fmaf(a1, b0, acc[1][0]); acc[1][1] = fmaf(a1, b1, acc[1][1]);
            acc[1][2] = fmaf(a1, b2, acc[1][2]); acc[1][3] = fmaf(a1, b3, acc[1][3]);
            acc[2][0] = fmaf(a2, b0, acc[2][0]); acc[2][1] = fmaf(a2, b1, acc[2][1]);
            acc[2][2] = fmaf(a2, b2, acc[2][2]); acc[2][3] = fmaf(a2, b3, acc[2][3]);
            acc[3][0] = fmaf(a3, b0, acc[3][0]); acc[3][1] = fmaf(a3, b1, acc[3][1]);
            acc[3][2] = fmaf(a3, b2, acc[3][2]); acc[3][3] = fmaf(a3, b3, acc[3][3]);
        }
        #pragma unroll
        for (int r = 0; r < 4; ++r) {
            int gi = ib + i0 + r;
            uchar4 m;
            m.x = (acc[r][0] != 0.f || gi == jb + j0 + 0) ? 1 : 0;
            m.y = (acc[r][1] != 0.f || gi == jb + j0 + 1) ? 1 : 0;
            m.z = (acc[r][2] != 0.f || gi == jb + j0 + 2) ? 1 : 0;
            m.w = (acc[r][3] != 0.f || gi == jb + j0 + 3) ? 1 : 0;
            *(uchar4*)&mask[gi * NN + jb + j0] = m;
        }
    } else {
        float* wl = SH;
        float* wr = SH + 4096;
        for (int t = tid; t < 4096; t += 256) { wl[t] = Wl[t]; wr[t] = Wr[t]; }
        __syncthreads();
        int r = (blockIdx.x - 256) * 4 + (tid >> 6);
        int c = tid & 63;
        float av = att[c];
        const float* arow = A + r * 64;
        float accl = 0.f, accr = 0.f;
        #pragma unroll
        for (int p = 0; p < 64; ++p) {
            float a = arow[p];
            accl = fmaf(a, wl[p * 64 + c], accl);
            accr = fmaf(a, wr[p * 64 + c], accr);
        }
        // permuted xl store: logical col c = h*16 + c4*4 + r  ->  c4*16 + h*4 + r
        int cp = (((c >> 2) & 3) << 4) | ((c >> 4) << 2) | (c & 3);
        xl[r * 64 + cp] = accl;
        xr[r * 64 + c] = accr;
        float t = dpp_rowsum16(accl * av);
        if ((c & 15) == 15) alE[(r << 2) | (c >> 4)] = 0.6f * LOG2E * t;
    }
}

// --- Kernel 2: fused flash GATv2 (head-per-lane) [+ next-layer GEMM] -----
// Round-8 attn body verbatim (verified, 130.4us total). FUSEG exploits the
// ROW-LOCAL attn1->gemm2 dependency: block bid computes hbuf rows
// bid*4..bid*4+3 completely, and gemm2's block bid consumes exactly those
// rows -> run gemm2 in the SAME block after the epilogue. Intra-block only
// (__syncthreads suffices); NO cross-block communication inside a kernel
// (round-9 lesson: grid-sync coherence across XCDs is not safely available).
// res goes through LDS (RES), hbuf global round-trip eliminated. Outputs
// go to FRESH buffers xl2/xr2/alE2 (xl1/xr1 still being read by other
// blocks). Per-row state = SEPARATE NAMED 16-float arrays (SROA rule).
template <bool RELU, bool FUSEG>
__global__ __launch_bounds__(256, 2) void k_attn(
    const float* __restrict__ xlp, const float* __restrict__ xr,
    const float* __restrict__ att, const float* __restrict__ alE,
    const float* __restrict__ bias, const unsigned char* __restrict__ mask,
    float* __restrict__ out,
    const float* __restrict__ Wl2, const float* __restrict__ Wr2,
    const float* __restrict__ att2,
    float* __restrict__ xl2, float* __restrict__ xr2, float* __restrict__ alE2)
{
    __shared__ float Opart[4][4][4][64];   // [ii][wave][jlgrp][p]
    __shared__ float Lpart[4][4][4][NHEAD];
    __shared__ float SHW[FUSEG ? 8192 : 1];     // next-layer weights
    __shared__ float RES[FUSEG ? 4 : 1][64];    // this block's 4 output rows

    int tid = threadIdx.x;
    int wave = tid >> 6, lane = tid & 63;
    int h = lane & 3, jl = lane >> 2;
    int b = blockIdx.x >> 8;
    int i0 = (blockIdx.x & 255) << 2;
    int j0 = (wave << 8) + (jl << 4);

    if constexpr (FUSEG) {
        // stage next-layer weights; the epilogue's __syncthreads() is the
        // barrier before first read.
        for (int t = tid; t < 4096; t += 256) { SHW[t] = Wl2[t]; SHW[4096 + t] = Wr2[t]; }
    }

    const float* xlb = xlp + (b << 16);

    // natural head-h slices: at[p] = att[h][p], xr?f[p] = xr[row][h*16+p]
    float at[16], xr0f[16], xr1f[16], xr2f[16], xr3f[16];
    {
        const float* ap = att + (h << 4);
        const float* r0 = xr + (((b << 10) + i0) << 6) + (h << 4);
        const float* r1 = r0 + 64;
        const float* r2 = r0 + 128;
        const float* r3 = r0 + 192;
        #pragma unroll
        for (int c = 0; c < 4; ++c) {
            *(float4*)&at[c << 2]   = *(const float4*)(ap + (c << 2));
            *(float4*)&xr0f[c << 2] = *(const float4*)(r0 + (c << 2));
            *(float4*)&xr1f[c << 2] = *(const float4*)(r1 + (c << 2));
            *(float4*)&xr2f[c << 2] = *(const float4*)(r2 + (c << 2));
            *(float4*)&xr3f[c << 2] = *(const float4*)(r3 + (c << 2));
        }
        #pragma unroll
        for (int p = 0; p < 16; ++p) at[p] *= 0.4f * LOG2E;
    }
    // arE per row, fully in-lane
    float ar0, ar1, ar2, ar3;
    {
        float s0[4], s1[4], s2[4], s3[4];
        #pragma unroll
        for (int c = 0; c < 4; ++c) {
            float t0 = 0.f, t1 = 0.f, t2 = 0.f, t3 = 0.f;
            #pragma unroll
            for (int r = 0; r < 4; ++r) {
                int p = (c << 2) + r;
                float a = at[p];
                t0 = fmaf(a, xr0f[p], t0);
                t1 = fmaf(a, xr1f[p], t1);
                t2 = fmaf(a, xr2f[p], t2);
                t3 = fmaf(a, xr3f[p], t3);
            }
            s0[c] = t0; s1[c] = t1; s2[c] = t2; s3[c] = t3;
        }
        ar0 = 1.5f * ((s0[0] + s0[1]) + (s0[2] + s0[3]));
        ar1 = 1.5f * ((s1[0] + s1[1]) + (s1[2] + s1[3]));
        ar2 = 1.5f * ((s2[0] + s2[1]) + (s2[2] + s2[3]));
        ar3 = 1.5f * ((s3[0] + s3[1]) + (s3[2] + s3[3]));
    }

    // pack this lane's 16 mask bytes into 16 bits, rows i0..i0+3
    unsigned mb0 = 0, mb1 = 0, mb2 = 0, mb3 = 0;
    {
        const unsigned* m0p = (const unsigned*)(mask + (i0 + 0) * NN + j0);
        const unsigned* m1p = (const unsigned*)(mask + (i0 + 1) * NN + j0);
        const unsigned* m2p = (const unsigned*)(mask + (i0 + 2) * NN + j0);
        const unsigned* m3p = (const unsigned*)(mask + (i0 + 3) * NN + j0);
        #pragma unroll
        for (int q = 0; q < 4; ++q) {
            unsigned w0 = m0p[q], w1 = m1p[q], w2 = m2p[q], w3 = m3p[q];
            mb0 |= ((((w0 >> 0) & 1) | ((w0 >> 7) & 2) | ((w0 >> 14) & 4) | ((w0 >> 21) & 8)) << (q << 2));
            mb1 |= ((((w1 >> 0) & 1) | ((w1 >> 7) & 2) | ((w1 >> 14) & 4) | ((w1 >> 21) & 8)) << (q << 2));
            mb2 |= ((((w2 >> 0) & 1) | ((w2 >> 7) & 2) | ((w2 >> 14) & 4) | ((w2 >> 21) & 8)) << (q << 2));
            mb3 |= ((((w3 >> 0) & 1) | ((w3 >> 7) & 2) | ((w3 >> 14) & 4) | ((w3 >> 21) & 8)) << (q << 2));
        }
    }

    float O0[16], O1[16], O2[16], O3[16];
    float lq0 = 0.f, lq1 = 0.f, lq2 = 0.f, lq3 = 0.f;
    #pragma unroll
    for (int p = 0; p < 16; ++p) { O0[p] = 0.f; O1[p] = 0.f; O2[p] = 0.f; O3[p] = 0.f; }

    const float* xrow = xlb + (j0 << 6) + (h << 2);
    const float* alp  = alE + (b << 12) + (j0 << 2) + h;

    #pragma unroll 2
    for (int s = 0; s < 16; ++s) {
        const float* rp = xrow + (s << 6);
        float xv[16];
        *(float4*)&xv[0]  = *(const float4*)(rp);
        *(float4*)&xv[4]  = *(const float4*)(rp + 16);
        *(float4*)&xv[8]  = *(const float4*)(rp + 32);
        *(float4*)&xv[12] = *(const float4*)(rp + 48);
        float alr = alp[s << 2];
        bool m0 = (mb0 >> s) & 1, m1 = (mb1 >> s) & 1;
        bool m2 = (mb2 >> s) & 1, m3 = (mb3 >> s) & 1;

        float s0[4], s1[4], s2[4], s3[4];
        #pragma unroll
        for (int c = 0; c < 4; ++c) {
            float t0 = 0.f, t1 = 0.f, t2 = 0.f, t3 = 0.f;
            #pragma unroll
            for (int r = 0; r < 4; ++r) {
                int p = (c << 2) + r;
                float a = at[p], xvv = xv[p];
                t0 = fmaf(a, __builtin_fabsf(xr0f[p] + xvv), t0);
                t1 = fmaf(a, __builtin_fabsf(xr1f[p] + xvv), t1);
                t2 = fmaf(a, __builtin_fabsf(xr2f[p] + xvv), t2);
                t3 = fmaf(a, __builtin_fabsf(xr3f[p] + xvv), t3);
            }
            s0[c] = t0; s1[c] = t1; s2[c] = t2; s3[c] = t3;
        }
        float e0 = ((s0[0] + s0[1]) + (s0[2] + s0[3])) + (ar0 + alr);
        float e1 = ((s1[0] + s1[1]) + (s1[2] + s1[3])) + (ar1 + alr);
        float e2 = ((s2[0] + s2[1]) + (s2[2] + s2[3])) + (ar2 + alr);
        float e3 = ((s3[0] + s3[1]) + (s3[2] + s3[3])) + (ar3 + alr);
        float pe0 = m0 ? __builtin_amdgcn_exp2f(e0) : 0.f;
        float pe1 = m1 ? __builtin_amdgcn_exp2f(e1) : 0.f;
        float pe2 = m2 ? __builtin_amdgcn_exp2f(e2) : 0.f;
        float pe3 = m3 ? __builtin_amdgcn_exp2f(e3) : 0.f;
        lq0 += pe0; lq1 += pe1; lq2 += pe2; lq3 += pe3;
        #pragma unroll
        for (int p = 0; p < 16; ++p) {
            float xvv = xv[p];
            O0[p] = fmaf(pe0, xvv, O0[p]);
            O1[p] = fmaf(pe1, xvv, O1[p]);
            O2[p] = fmaf(pe2, xvv, O2[p]);
            O3[p] = fmaf(pe3, xvv, O3[p]);
        }
    }

    // reduce over the 4 jl's within each 16-lane DPP row (stride-4 lanes)
    #pragma unroll
    for (int p = 0; p < 16; ++p) {
        O0[p] += dpp_mov<0x114>(O0[p]);  O0[p] += dpp_mov<0x118>(O0[p]);
        O1[p] += dpp_mov<0x114>(O1[p]);  O1[p] += dpp_mov<0x118>(O1[p]);
        O2[p] += dpp_mov<0x114>(O2[p]);  O2[p] += dpp_mov<0x118>(O2[p]);
        O3[p] += dpp_mov<0x114>(O3[p]);  O3[p] += dpp_mov<0x118>(O3[p]);
    }
    lq0 += dpp_mov<0x114>(lq0);  lq0 += dpp_mov<0x118>(lq0);
    lq1 += dpp_mov<0x114>(lq1);  lq1 += dpp_mov<0x118>(lq1);
    lq2 += dpp_mov<0x114>(lq2);  lq2 += dpp_mov<0x118>(lq2);
    lq3 += dpp_mov<0x114>(lq3);  lq3 += dpp_mov<0x118>(lq3);

    if ((lane & 15) >= 12) {             // lanes 12..15 of each DPP row
        int k = lane >> 4;               // jl-group
        #pragma unroll
        for (int c = 0; c < 4; ++c) {
            *(float4*)&Opart[0][wave][k][(h << 4) + (c << 2)] = *(const float4*)&O0[c << 2];
            *(float4*)&Opart[1][wave][k][(h << 4) + (c << 2)] = *(const float4*)&O1[c << 2];
            *(float4*)&Opart[2][wave][k][(h << 4) + (c << 2)] = *(const float4*)&O2[c << 2];
            *(float4*)&Opart[3][wave][k][(h << 4) + (c << 2)] = *(const float4*)&O3[c << 2];
        }
        Lpart[0][wave][k][h] = lq0;
        Lpart[1][wave][k][h] = lq1;
        Lpart[2][wave][k][h] = lq2;
        Lpart[3][wave][k][h] = lq3;
    }
    __syncthreads();

    {
        int ii = tid >> 6, c = tid & 63;
        float o = 0.f, l = 0.f;
        #pragma unroll
        for (int w = 0; w < 4; ++w)
            #pragma unroll
            for (int k = 0; k < 4; ++k) {
                o += Opart[ii][w][k][c];
                l += Lpart[ii][w][k][c >> 4];
            }
        float res = o / l + bias[c];
        if (RELU) res = fmaxf(res, 0.f);
        if constexpr (FUSEG) {
            RES[ii][c] = res;            // hbuf never touches global
        } else {
            out[((b << 10) + i0 + ii) * D + c] = res;
        }
    }

    if constexpr (FUSEG) {
        __syncthreads();
        // next-layer dual GEMM on this block's 4 rows (row-local dep):
        // global row rr = blockIdx.x*4 + ii  ==  b*1024 + i0 + ii.
        int ii = tid >> 6, c = tid & 63;
        int rr = (blockIdx.x << 2) + ii;
        float av = att2[c];
        const float* arow = &RES[ii][0];
        float accl = 0.f, accr = 0.f;
        #pragma unroll
        for (int p = 0; p < 64; ++p) {
            float a = arow[p];                    // LDS broadcast read
            accl = fmaf(a, SHW[p * 64 + c], accl);
            accr = fmaf(a, SHW[4096 + p * 64 + c], accr);
        }
        int cp = (((c >> 2) & 3) << 4) | ((c >> 4) << 2) | (c & 3);
        xl2[rr * 64 + cp] = accl;
        xr2[rr * 64 + c] = accr;
        float t = dpp_rowsum16(accl * av);
        if ((c & 15) == 15) alE2[(rr << 2) | (c >> 4)] = 0.6f * LOG2E * t;
    }
}

extern "C" void kernel_launch(void* const* d_in, const int* in_sizes, int n_in,
                              void* d_out, int out_size, void* d_ws, size_t ws_size,
                              hipStream_t stream) {
    const float* x    = (const float*)d_in[0];
    const float* emb  = (const float*)d_in[1];
    const float* Wl1  = (const float*)d_in[2];
    const float* Wr1  = (const float*)d_in[3];
    const float* att1 = (const float*)d_in[4];
    const float* b1   = (const float*)d_in[5];
    const float* Wl2  = (const float*)d_in[6];
    const float* Wr2  = (const float*)d_in[7];
    const float* att2 = (const float*)d_in[8];
    const float* b2   = (const float*)d_in[9];
    float* out = (float*)d_out;

    unsigned char* mask = (unsigned char*)d_ws;                 // 1MB
    float* xl   = (float*)(mask + NN * NN);                     // 512KB (permuted)
    float* xr   = xl + BB * NN * D;                             // 512KB
    float* xl2  = xr + BB * NN * D;                             // 512KB (permuted)
    float* alE  = xl2 + BB * NN * D;                            // 32KB
    float* xr2  = alE + BB * NN * NHEAD;                        // 512KB
    float* alE2 = xr2 + BB * NN * D;                            // 32KB

    k_mask_gemm<<<256 + BB * NN / 4, 256, 0, stream>>>(emb, mask, x, Wl1, Wr1, att1, xl, xr, alE);

    // attn layer 1 (relu) + fused layer-2 dual GEMM (row-local dependency)
    k_attn<true, true><<<BB * NN / 4, 256, 0, stream>>>(
        xl, xr, att1, alE, b1, mask, xl2 /*unused out*/,
        Wl2, Wr2, att2, xl2, xr2, alE2);

    // attn layer 2 -> final output
    k_attn<false, false><<<BB * NN / 4, 256, 0, stream>>>(
        xl2, xr2, att2, alE2, b2, mask, out,
        Wl2, Wr2, att2, xl2, xr2, alE2 /*unused*/);
}

// Round 11
// 121.251 us; speedup vs baseline: 1.1238x; 1.0573x over previous
//
#include <hip/hip_runtime.h>
#include <math.h>

#define NN 1024
#define BB 2
#define D 64
#define NHEAD 4
#define LOG2E 1.4426950408889634f
#define MST 65

template <int CTRL>
__device__ __forceinline__ float dpp_mov(float x) {
    int xi = __builtin_bit_cast(int, x);
    int r = __builtin_amdgcn_update_dpp(0, xi, CTRL, 0xF, 0xF, true);
    return __builtin_bit_cast(float, r);
}
template <int CTRL>
__device__ __forceinline__ unsigned dpp_movi(unsigned x) {
    int r = __builtin_amdgcn_update_dpp(0, (int)x, CTRL, 0xF, 0xF, true);
    return (unsigned)r;
}

// 16-lane row sum; valid in lane 15 of each row of 16.
__device__ __forceinline__ float dpp_rowsum16(float t) {
    t += dpp_mov<0x111>(t);
    t += dpp_mov<0x112>(t);
    t += dpp_mov<0x114>(t);
    t += dpp_mov<0x118>(t);
    return t;
}

// --- Kernel 1: merged {adjacency mask GEMM} + {layer-1 dual GEMM} --------
// (round-8 verbatim, verified)
__global__ __launch_bounds__(256) void k_mask_gemm(
    const float* __restrict__ emb, unsigned char* __restrict__ mask,
    const float* __restrict__ A, const float* __restrict__ Wl,
    const float* __restrict__ Wr, const float* __restrict__ att,
    float* __restrict__ xl, float* __restrict__ xr, float* __restrict__ alE)
{
    __shared__ float SH[64 * MST * 2];
    int tid = threadIdx.x;
    if (blockIdx.x < 256) {
        float* As = SH;
        float* Bs = SH + 64 * MST;
        int ib = (blockIdx.x & 15) << 6;
        int jb = (blockIdx.x >> 4) << 6;

        #pragma unroll
        for (int r = 0; r < 4; ++r) {
            int q = tid + (r << 8);
            int row = q >> 4, c4 = (q & 15) << 2;
            float4 a = *(const float4*)&emb[(ib + row) * D + c4];
            float4 b = *(const float4*)&emb[(jb + row) * D + c4];
            As[row * MST + c4 + 0] = a.x; As[row * MST + c4 + 1] = a.y;
            As[row * MST + c4 + 2] = a.z; As[row * MST + c4 + 3] = a.w;
            Bs[row * MST + c4 + 0] = b.x; Bs[row * MST + c4 + 1] = b.y;
            Bs[row * MST + c4 + 2] = b.z; Bs[row * MST + c4 + 3] = b.w;
        }
        __syncthreads();

        int i0 = (tid >> 4) << 2;
        int j0 = (tid & 15) << 2;
        float acc[4][4] = {};
        #pragma unroll 8
        for (int k = 0; k < 64; ++k) {
            float a0 = As[(i0 + 0) * MST + k];
            float a1 = As[(i0 + 1) * MST + k];
            float a2 = As[(i0 + 2) * MST + k];
            float a3 = As[(i0 + 3) * MST + k];
            float b0 = Bs[(j0 + 0) * MST + k];
            float b1 = Bs[(j0 + 1) * MST + k];
            float b2 = Bs[(j0 + 2) * MST + k];
            float b3 = Bs[(j0 + 3) * MST + k];
            acc[0][0] = fmaf(a0, b0, acc[0][0]); acc[0][1] = fmaf(a0, b1, acc[0][1]);
            acc[0][2] = fmaf(a0, b2, acc[0][2]); acc[0][3] = fmaf(a0, b3, acc[0][3]);
            acc[1][0] = fmaf(a1, b0, acc[1][0]); acc[1][1] = fmaf(a1, b1, acc[1][1]);
            acc[1][2] = fmaf(a1, b2, acc[1][2]); acc[1][3] = fmaf(a1, b3, acc[1][3]);
            acc[2][0] = fmaf(a2, b0, acc[2][0]); acc[2][1] = fmaf(a2, b1, acc[2][1]);
            acc[2][2] = fmaf(a2, b2, acc[2][2]); acc[2][3] = fmaf(a2, b3, acc[2][3]);
            acc[3][0] = fmaf(a3, b0, acc[3][0]); acc[3][1] = fmaf(a3, b1, acc[3][1]);
            acc[3][2] = fmaf(a3, b2, acc[3][2]); acc[3][3] = fmaf(a3, b3, acc[3][3]);
        }
        #pragma unroll
        for (int r = 0; r < 4; ++r) {
            int gi = ib + i0 + r;
            uchar4 m;
            m.x = (acc[r][0] != 0.f || gi == jb + j0 + 0) ? 1 : 0;
            m.y = (acc[r][1] != 0.f || gi == jb + j0 + 1) ? 1 : 0;
            m.z = (acc[r][2] != 0.f || gi == jb + j0 + 2) ? 1 : 0;
            m.w = (acc[r][3] != 0.f || gi == jb + j0 + 3) ? 1 : 0;
            *(uchar4*)&mask[gi * NN + jb + j0] = m;
        }
    } else {
        float* wl = SH;
        float* wr = SH + 4096;
        for (int t = tid; t < 4096; t += 256) { wl[t] = Wl[t]; wr[t] = Wr[t]; }
        __syncthreads();
        int r = (blockIdx.x - 256) * 4 + (tid >> 6);
        int c = tid & 63;
        float av = att[c];
        const float* arow = A + r * 64;
        float accl = 0.f, accr = 0.f;
        #pragma unroll
        for (int p = 0; p < 64; ++p) {
            float a = arow[p];
            accl = fmaf(a, wl[p * 64 + c], accl);
            accr = fmaf(a, wr[p * 64 + c], accr);
        }
        // permuted xl store: logical col c = h*16 + c4*4 + r  ->  c4*16 + h*4 + r
        int cp = (((c >> 2) & 3) << 4) | ((c >> 4) << 2) | (c & 3);
        xl[r * 64 + cp] = accl;
        xr[r * 64 + c] = accr;
        float t = dpp_rowsum16(accl * av);
        if ((c & 15) == 15) alE[(r << 2) | (c >> 4)] = 0.6f * LOG2E * t;
    }
}

// --- Kernel 2: fused flash GATv2, head-per-lane, DENSE-TILE staging ------
// Theory (r5/r6/r8 all ~35us despite -33% instr / async-LDS / occupancy
// changes): attn is bound by per-CU memory TRANSACTION throughput - the
// old xv loads gathered 16 scattered 64B segments per instruction. Fix:
// relabel j-ownership (lane jl handles j = wave*256 + s*16 + jl) so each
// s-iter consumes one DENSE 16-row (4KB) tile; stage it reg->LDS double-
// buffered (wave-private, barrier-free). Global loads: 4 dense 1KB instrs
// per tile (4x fewer, 4x larger segments). ds_read uses a 3-bit XOR
// swizzle (slot ^= (row&3) | ((row>>2&1)<<2)) -> conflict-free.
// Per-pair math is instruction-identical to round 10 (bit-identical e/pe);
// only the j-accumulation ORDER of l/O changes (fp delta ~1e-5 << 1.8e-3).
// Per-row state = SEPARATE NAMED 16-float arrays (SROA rule, rounds 2-3).
// FUSEG (row-local attn1->gemm2, r10-verified): SHW now UNIONS with the
// tile buffer XS (both 32KB; XS dead after the s-loop; barrier-separated).
template <bool RELU, bool FUSEG>
__global__ __launch_bounds__(256, 2) void k_attn(
    const float* __restrict__ xlp, const float* __restrict__ xr,
    const float* __restrict__ att, const float* __restrict__ alE,
    const float* __restrict__ bias, const unsigned char* __restrict__ mask,
    float* __restrict__ out,
    const float* __restrict__ Wl2, const float* __restrict__ Wr2,
    const float* __restrict__ att2,
    float* __restrict__ xl2, float* __restrict__ xr2, float* __restrict__ alE2)
{
    __shared__ __align__(16) float XS[8192];    // XBUF[4][2][1024] then SHW
    __shared__ float Opart[4][4][4][64];        // [ii][wave][jlgrp][p]
    __shared__ float Lpart[4][4][4][NHEAD];
    __shared__ float RES[4][64];                // FUSEG: block's 4 out rows

    int tid = threadIdx.x;
    int wave = tid >> 6, lane = tid & 63;
    int h = lane & 3, jl = lane >> 2;
    int b = blockIdx.x >> 8;
    int i0 = (blockIdx.x & 255) << 2;

    const float* xlb = xlp + (b << 16);

    // natural head-h slices: at[p] = att[h][p], xr?f[p] = xr[row][h*16+p]
    float at[16], xr0f[16], xr1f[16], xr2f[16], xr3f[16];
    {
        const float* ap = att + (h << 4);
        const float* r0 = xr + (((b << 10) + i0) << 6) + (h << 4);
        const float* r1 = r0 + 64;
        const float* r2 = r0 + 128;
        const float* r3 = r0 + 192;
        #pragma unroll
        for (int c = 0; c < 4; ++c) {
            *(float4*)&at[c << 2]   = *(const float4*)(ap + (c << 2));
            *(float4*)&xr0f[c << 2] = *(const float4*)(r0 + (c << 2));
            *(float4*)&xr1f[c << 2] = *(const float4*)(r1 + (c << 2));
            *(float4*)&xr2f[c << 2] = *(const float4*)(r2 + (c << 2));
            *(float4*)&xr3f[c << 2] = *(const float4*)(r3 + (c << 2));
        }
        #pragma unroll
        for (int p = 0; p < 16; ++p) at[p] *= 0.4f * LOG2E;
    }
    // arE per row, fully in-lane (unchanged)
    float ar0, ar1, ar2, ar3;
    {
        float s0[4], s1[4], s2[4], s3[4];
        #pragma unroll
        for (int c = 0; c < 4; ++c) {
            float t0 = 0.f, t1 = 0.f, t2 = 0.f, t3 = 0.f;
            #pragma unroll
            for (int r = 0; r < 4; ++r) {
                int p = (c << 2) + r;
                float a = at[p];
                t0 = fmaf(a, xr0f[p], t0);
                t1 = fmaf(a, xr1f[p], t1);
                t2 = fmaf(a, xr2f[p], t2);
                t3 = fmaf(a, xr3f[p], t3);
            }
            s0[c] = t0; s1[c] = t1; s2[c] = t2; s3[c] = t3;
        }
        ar0 = 1.5f * ((s0[0] + s0[1]) + (s0[2] + s0[3]));
        ar1 = 1.5f * ((s1[0] + s1[1]) + (s1[2] + s1[3]));
        ar2 = 1.5f * ((s2[0] + s2[1]) + (s2[2] + s2[3]));
        ar3 = 1.5f * ((s3[0] + s3[1]) + (s3[2] + s3[3]));
    }

    // mask bits for j = wave*256 + s*16 + jl: lane gathers 4 bytes per row
    // (s in {4h..4h+3}), then quad-OR (DPP butterflies) merges all 16 bits.
    unsigned mb0, mb1, mb2, mb3;
    {
        const unsigned char* mp = mask + i0 * NN + (wave << 8) + jl;
        int hh = h << 6;                 // (4h)*16 bytes
        unsigned n0 = (unsigned)mp[hh] | ((unsigned)mp[hh + 16] << 1)
                    | ((unsigned)mp[hh + 32] << 2) | ((unsigned)mp[hh + 48] << 3);
        mp += NN;
        unsigned n1 = (unsigned)mp[hh] | ((unsigned)mp[hh + 16] << 1)
                    | ((unsigned)mp[hh + 32] << 2) | ((unsigned)mp[hh + 48] << 3);
        mp += NN;
        unsigned n2 = (unsigned)mp[hh] | ((unsigned)mp[hh + 16] << 1)
                    | ((unsigned)mp[hh + 32] << 2) | ((unsigned)mp[hh + 48] << 3);
        mp += NN;
        unsigned n3 = (unsigned)mp[hh] | ((unsigned)mp[hh + 16] << 1)
                    | ((unsigned)mp[hh + 32] << 2) | ((unsigned)mp[hh + 48] << 3);
        unsigned v0 = n0 << (h << 2), v1 = n1 << (h << 2);
        unsigned v2 = n2 << (h << 2), v3 = n3 << (h << 2);
        v0 |= dpp_movi<0xB1>(v0); v0 |= dpp_movi<0x4E>(v0);
        v1 |= dpp_movi<0xB1>(v1); v1 |= dpp_movi<0x4E>(v1);
        v2 |= dpp_movi<0xB1>(v2); v2 |= dpp_movi<0x4E>(v2);
        v3 |= dpp_movi<0xB1>(v3); v3 |= dpp_movi<0x4E>(v3);
        mb0 = v0; mb1 = v1; mb2 = v2; mb3 = v3;
    }

    float O0[16], O1[16], O2[16], O3[16];
    float lq0 = 0.f, lq1 = 0.f, lq2 = 0.f, lq3 = 0.f;
    #pragma unroll
    for (int p = 0; p < 16; ++p) { O0[p] = 0.f; O1[p] = 0.f; O2[p] = 0.f; O3[p] = 0.f; }

    // --- dense-tile staging setup ---
    const float* tb = xlb + (wave << 14);     // wave's 256 rows (16 tiles)
    float* XB = XS + (wave << 11);            // wave-private [2][1024]
    int l4 = lane << 2;
    // write addrs (swizzle: slot' = slot ^ (row&3) ^ ((row>>2&1)<<2)):
    //   piece k covers rows 4k+(lane>>4); slot = lane&15.
    int rowoff = (lane >> 4) << 6;
    int sb = (lane & 15) ^ (lane >> 4);
    int A0 = rowoff + (sb << 2);
    int A1 = rowoff + ((sb ^ 4) << 2);
    // read addrs: row = jl; logical slot h+4q at slot' field
    int qx = (jl >> 2) & 1;
    int rb = (jl << 6) + ((h ^ (jl & 3)) << 2);
    const float* alp = alE + (b << 12) + (wave << 10) + lane;

    float4 ga, gb, gc, gd;
    {   // tile 0 -> regs -> buf0; tile 1 -> regs
        const float* p = tb + l4;
        ga = *(const float4*)p;       gb = *(const float4*)(p + 256);
        gc = *(const float4*)(p + 512); gd = *(const float4*)(p + 768);
        *(float4*)&XB[A0] = ga;         *(float4*)&XB[256 + A1] = gb;
        *(float4*)&XB[512 + A0] = gc;   *(float4*)&XB[768 + A1] = gd;
        p = tb + 1024 + l4;
        ga = *(const float4*)p;       gb = *(const float4*)(p + 256);
        gc = *(const float4*)(p + 512); gd = *(const float4*)(p + 768);
    }

    #pragma unroll 2
    for (int s = 0; s < 16; ++s) {
        if (s < 15) {                  // write tile s+1 from regs
            float* w = XB + (((s + 1) & 1) << 10);
            *(float4*)&w[A0] = ga;         *(float4*)&w[256 + A1] = gb;
            *(float4*)&w[512 + A0] = gc;   *(float4*)&w[768 + A1] = gd;
        }
        if (s < 14) {                  // load tile s+2 -> regs
            const float* p = tb + ((s + 2) << 10) + l4;
            ga = *(const float4*)p;       gb = *(const float4*)(p + 256);
            gc = *(const float4*)(p + 512); gd = *(const float4*)(p + 768);
        }

        const float* XBr = XB + ((s & 1) << 10);
        float xv[16];
        *(float4*)&xv[0]  = *(const float4*)&XBr[rb + (((0 ^ qx)) << 4)];
        *(float4*)&xv[4]  = *(const float4*)&XBr[rb + (((1 ^ qx)) << 4)];
        *(float4*)&xv[8]  = *(const float4*)&XBr[rb + (((2 ^ qx)) << 4)];
        *(float4*)&xv[12] = *(const float4*)&XBr[rb + (((3 ^ qx)) << 4)];
        float alr = alp[s << 6];
        bool m0 = (mb0 >> s) & 1, m1 = (mb1 >> s) & 1;
        bool m2 = (mb2 >> s) & 1, m3 = (mb3 >> s) & 1;

        float s0[4], s1[4], s2[4], s3[4];
        #pragma unroll
        for (int c = 0; c < 4; ++c) {
            float t0 = 0.f, t1 = 0.f, t2 = 0.f, t3 = 0.f;
            #pragma unroll
            for (int r = 0; r < 4; ++r) {
                int p = (c << 2) + r;
                float a = at[p], xvv = xv[p];
                t0 = fmaf(a, __builtin_fabsf(xr0f[p] + xvv), t0);
                t1 = fmaf(a, __builtin_fabsf(xr1f[p] + xvv), t1);
                t2 = fmaf(a, __builtin_fabsf(xr2f[p] + xvv), t2);
                t3 = fmaf(a, __builtin_fabsf(xr3f[p] + xvv), t3);
            }
            s0[c] = t0; s1[c] = t1; s2[c] = t2; s3[c] = t3;
        }
        float e0 = ((s0[0] + s0[1]) + (s0[2] + s0[3])) + (ar0 + alr);
        float e1 = ((s1[0] + s1[1]) + (s1[2] + s1[3])) + (ar1 + alr);
        float e2 = ((s2[0] + s2[1]) + (s2[2] + s2[3])) + (ar2 + alr);
        float e3 = ((s3[0] + s3[1]) + (s3[2] + s3[3])) + (ar3 + alr);
        float pe0 = m0 ? __builtin_amdgcn_exp2f(e0) : 0.f;
        float pe1 = m1 ? __builtin_amdgcn_exp2f(e1) : 0.f;
        float pe2 = m2 ? __builtin_amdgcn_exp2f(e2) : 0.f;
        float pe3 = m3 ? __builtin_amdgcn_exp2f(e3) : 0.f;
        lq0 += pe0; lq1 += pe1; lq2 += pe2; lq3 += pe3;
        #pragma unroll
        for (int p = 0; p < 16; ++p) {
            float xvv = xv[p];
            O0[p] = fmaf(pe0, xvv, O0[p]);
            O1[p] = fmaf(pe1, xvv, O1[p]);
            O2[p] = fmaf(pe2, xvv, O2[p]);
            O3[p] = fmaf(pe3, xvv, O3[p]);
        }
    }

    if constexpr (FUSEG) {
        __syncthreads();               // all waves done reading XS tiles
        for (int t = tid; t < 4096; t += 256) { XS[t] = Wl2[t]; XS[4096 + t] = Wr2[t]; }
    }

    // reduce over the 4 jl's within each 16-lane DPP row (stride-4 lanes)
    #pragma unroll
    for (int p = 0; p < 16; ++p) {
        O0[p] += dpp_mov<0x114>(O0[p]);  O0[p] += dpp_mov<0x118>(O0[p]);
        O1[p] += dpp_mov<0x114>(O1[p]);  O1[p] += dpp_mov<0x118>(O1[p]);
        O2[p] += dpp_mov<0x114>(O2[p]);  O2[p] += dpp_mov<0x118>(O2[p]);
        O3[p] += dpp_mov<0x114>(O3[p]);  O3[p] += dpp_mov<0x118>(O3[p]);
    }
    lq0 += dpp_mov<0x114>(lq0);  lq0 += dpp_mov<0x118>(lq0);
    lq1 += dpp_mov<0x114>(lq1);  lq1 += dpp_mov<0x118>(lq1);
    lq2 += dpp_mov<0x114>(lq2);  lq2 += dpp_mov<0x118>(lq2);
    lq3 += dpp_mov<0x114>(lq3);  lq3 += dpp_mov<0x118>(lq3);

    if ((lane & 15) >= 12) {             // lanes 12..15 of each DPP row
        int k = lane >> 4;               // jl-group
        #pragma unroll
        for (int c = 0; c < 4; ++c) {
            *(float4*)&Opart[0][wave][k][(h << 4) + (c << 2)] = *(const float4*)&O0[c << 2];
            *(float4*)&Opart[1][wave][k][(h << 4) + (c << 2)] = *(const float4*)&O1[c << 2];
            *(float4*)&Opart[2][wave][k][(h << 4) + (c << 2)] = *(const float4*)&O2[c << 2];
            *(float4*)&Opart[3][wave][k][(h << 4) + (c << 2)] = *(const float4*)&O3[c << 2];
        }
        Lpart[0][wave][k][h] = lq0;
        Lpart[1][wave][k][h] = lq1;
        Lpart[2][wave][k][h] = lq2;
        Lpart[3][wave][k][h] = lq3;
    }
    __syncthreads();                     // covers Opart/Lpart (+ SHW stage)

    {
        int ii = tid >> 6, c = tid & 63;
        float o = 0.f, l = 0.f;
        #pragma unroll
        for (int w = 0; w < 4; ++w)
            #pragma unroll
            for (int k = 0; k < 4; ++k) {
                o += Opart[ii][w][k][c];
                l += Lpart[ii][w][k][c >> 4];
            }
        float res = o / l + bias[c];
        if (RELU) res = fmaxf(res, 0.f);
        if constexpr (FUSEG) {
            RES[ii][c] = res;            // hbuf never touches global
        } else {
            out[((b << 10) + i0 + ii) * D + c] = res;
        }
    }

    if constexpr (FUSEG) {
        __syncthreads();
        // next-layer dual GEMM on this block's 4 rows (row-local dep)
        int ii = tid >> 6, c = tid & 63;
        int rr = (blockIdx.x << 2) + ii;
        float av = att2[c];
        const float* arow = &RES[ii][0];
        float accl = 0.f, accr = 0.f;
        #pragma unroll
        for (int p = 0; p < 64; ++p) {
            float a = arow[p];                    // LDS broadcast read
            accl = fmaf(a, XS[p * 64 + c], accl);
            accr = fmaf(a, XS[4096 + p * 64 + c], accr);
        }
        int cp = (((c >> 2) & 3) << 4) | ((c >> 4) << 2) | (c & 3);
        xl2[rr * 64 + cp] = accl;
        xr2[rr * 64 + c] = accr;
        float t = dpp_rowsum16(accl * av);
        if ((c & 15) == 15) alE2[(rr << 2) | (c >> 4)] = 0.6f * LOG2E * t;
    }
}

extern "C" void kernel_launch(void* const* d_in, const int* in_sizes, int n_in,
                              void* d_out, int out_size, void* d_ws, size_t ws_size,
                              hipStream_t stream) {
    const float* x    = (const float*)d_in[0];
    const float* emb  = (const float*)d_in[1];
    const float* Wl1  = (const float*)d_in[2];
    const float* Wr1  = (const float*)d_in[3];
    const float* att1 = (const float*)d_in[4];
    const float* b1   = (const float*)d_in[5];
    const float* Wl2  = (const float*)d_in[6];
    const float* Wr2  = (const float*)d_in[7];
    const float* att2 = (const float*)d_in[8];
    const float* b2   = (const float*)d_in[9];
    float* out = (float*)d_out;

    unsigned char* mask = (unsigned char*)d_ws;                 // 1MB
    float* xl   = (float*)(mask + NN * NN);                     // 512KB (permuted)
    float* xr   = xl + BB * NN * D;                             // 512KB
    float* xl2  = xr + BB * NN * D;                             // 512KB (permuted)
    float* alE  = xl2 + BB * NN * D;                            // 32KB
    float* xr2  = alE + BB * NN * NHEAD;                        // 512KB
    float* alE2 = xr2 + BB * NN * D;                            // 32KB

    k_mask_gemm<<<256 + BB * NN / 4, 256, 0, stream>>>(emb, mask, x, Wl1, Wr1, att1, xl, xr, alE);

    // attn layer 1 (relu) + fused layer-2 dual GEMM (row-local dependency)
    k_attn<true, true><<<BB * NN / 4, 256, 0, stream>>>(
        xl, xr, att1, alE, b1, mask, xl2 /*unused out*/,
        Wl2, Wr2, att2, xl2, xr2, alE2);

    // attn layer 2 -> final output
    k_attn<false, false><<<BB * NN / 4, 256, 0, stream>>>(
        xl2, xr2, att2, alE2, b2, mask, out,
        Wl2, Wr2, att2, xl2, xr2, alE2 /*unused*/);
}

// Round 12
// 121.143 us; speedup vs baseline: 1.1248x; 1.0009x over previous
//
#include <hip/hip_runtime.h>
#include <math.h>

#define NN 1024
#define BB 2
#define D 64
#define NHEAD 4
#define LOG2E 1.4426950408889634f
#define MST 65

template <int CTRL>
__device__ __forceinline__ float dpp_mov(float x) {
    int xi = __builtin_bit_cast(int, x);
    int r = __builtin_amdgcn_update_dpp(0, xi, CTRL, 0xF, 0xF, true);
    return __builtin_bit_cast(float, r);
}
template <int CTRL>
__device__ __forceinline__ unsigned dpp_movi(unsigned x) {
    int r = __builtin_amdgcn_update_dpp(0, (int)x, CTRL, 0xF, 0xF, true);
    return (unsigned)r;
}

// 16-lane row sum; valid in lane 15 of each row of 16.
__device__ __forceinline__ float dpp_rowsum16(float t) {
    t += dpp_mov<0x111>(t);
    t += dpp_mov<0x112>(t);
    t += dpp_mov<0x114>(t);
    t += dpp_mov<0x118>(t);
    return t;
}

// --- Kernel 1: merged {adjacency mask GEMM} + {layer-1 dual GEMM} --------
// (round-8 verbatim, verified)
__global__ __launch_bounds__(256) void k_mask_gemm(
    const float* __restrict__ emb, unsigned char* __restrict__ mask,
    const float* __restrict__ A, const float* __restrict__ Wl,
    const float* __restrict__ Wr, const float* __restrict__ att,
    float* __restrict__ xl, float* __restrict__ xr, float* __restrict__ alE)
{
    __shared__ float SH[64 * MST * 2];
    int tid = threadIdx.x;
    if (blockIdx.x < 256) {
        float* As = SH;
        float* Bs = SH + 64 * MST;
        int ib = (blockIdx.x & 15) << 6;
        int jb = (blockIdx.x >> 4) << 6;

        #pragma unroll
        for (int r = 0; r < 4; ++r) {
            int q = tid + (r << 8);
            int row = q >> 4, c4 = (q & 15) << 2;
            float4 a = *(const float4*)&emb[(ib + row) * D + c4];
            float4 b = *(const float4*)&emb[(jb + row) * D + c4];
            As[row * MST + c4 + 0] = a.x; As[row * MST + c4 + 1] = a.y;
            As[row * MST + c4 + 2] = a.z; As[row * MST + c4 + 3] = a.w;
            Bs[row * MST + c4 + 0] = b.x; Bs[row * MST + c4 + 1] = b.y;
            Bs[row * MST + c4 + 2] = b.z; Bs[row * MST + c4 + 3] = b.w;
        }
        __syncthreads();

        int i0 = (tid >> 4) << 2;
        int j0 = (tid & 15) << 2;
        float acc[4][4] = {};
        #pragma unroll 8
        for (int k = 0; k < 64; ++k) {
            float a0 = As[(i0 + 0) * MST + k];
            float a1 = As[(i0 + 1) * MST + k];
            float a2 = As[(i0 + 2) * MST + k];
            float a3 = As[(i0 + 3) * MST + k];
            float b0 = Bs[(j0 + 0) * MST + k];
            float b1 = Bs[(j0 + 1) * MST + k];
            float b2 = Bs[(j0 + 2) * MST + k];
            float b3 = Bs[(j0 + 3) * MST + k];
            acc[0][0] = fmaf(a0, b0, acc[0][0]); acc[0][1] = fmaf(a0, b1, acc[0][1]);
            acc[0][2] = fmaf(a0, b2, acc[0][2]); acc[0][3] = fmaf(a0, b3, acc[0][3]);
            acc[1][0] = fmaf(a1, b0, acc[1][0]); acc[1][1] = fmaf(a1, b1, acc[1][1]);
            acc[1][2] = fmaf(a1, b2, acc[1][2]); acc[1][3] = fmaf(a1, b3, acc[1][3]);
            acc[2][0] = fmaf(a2, b0, acc[2][0]); acc[2][1] = fmaf(a2, b1, acc[2][1]);
            acc[2][2] = fmaf(a2, b2, acc[2][2]); acc[2][3] = fmaf(a2, b3, acc[2][3]);
            acc[3][0] = fmaf(a3, b0, acc[3][0]); acc[3][1] = fmaf(a3, b1, acc[3][1]);
            acc[3][2] = fmaf(a3, b2, acc[3][2]); acc[3][3] = fmaf(a3, b3, acc[3][3]);
        }
        #pragma unroll
        for (int r = 0; r < 4; ++r) {
            int gi = ib + i0 + r;
            uchar4 m;
            m.x = (acc[r][0] != 0.f || gi == jb + j0 + 0) ? 1 : 0;
            m.y = (acc[r][1] != 0.f || gi == jb + j0 + 1) ? 1 : 0;
            m.z = (acc[r][2] != 0.f || gi == jb + j0 + 2) ? 1 : 0;
            m.w = (acc[r][3] != 0.f || gi == jb + j0 + 3) ? 1 : 0;
            *(uchar4*)&mask[gi * NN + jb + j0] = m;
        }
    } else {
        float* wl = SH;
        float* wr = SH + 4096;
        for (int t = tid; t < 4096; t += 256) { wl[t] = Wl[t]; wr[t] = Wr[t]; }
        __syncthreads();
        int r = (blockIdx.x - 256) * 4 + (tid >> 6);
        int c = tid & 63;
        float av = att[c];
        const float* arow = A + r * 64;
        float accl = 0.f, accr = 0.f;
        #pragma unroll
        for (int p = 0; p < 64; ++p) {
            float a = arow[p];
            accl = fmaf(a, wl[p * 64 + c], accl);
            accr = fmaf(a, wr[p * 64 + c], accr);
        }
        // permuted xl store: logical col c = h*16 + c4*4 + r  ->  c4*16 + h*4 + r
        int cp = (((c >> 2) & 3) << 4) | ((c >> 4) << 2) | (c & 3);
        xl[r * 64 + cp] = accl;
        xr[r * 64 + c] = accr;
        float t = dpp_rowsum16(accl * av);
        if ((c & 15) == 15) alE[(r << 2) | (c >> 4)] = 0.6f * LOG2E * t;
    }
}

// --- Kernel 2: fused flash GATv2, head-per-lane, dense tiles, 2-DEEP -----
// r11 (+7us) proved attn is memory-path-bound. Residual stall theory: xl
// comes from L3/HBM after the kernel boundary (cross-XCD writes, caches
// maintained between dispatches; L3 ~600-900cy), and r11's pipeline gave
// tile loads only ONE iteration (~1000cy) of flight before the LDS write
// drains vmcnt -> residual latency exposed serially every iter. Fix: TWO
// register sets A/B; at iter s write tile s+1 from one set, then reload
// that set with tile s+3 -> flight = 2 iters (~2000cy) > worst latency.
// +16 VGPR (~206 live < 256 cap). Buffers/swizzle/math identical to r11
// (xv bit-identical -> absmax must stay 3.814697e-06 exactly).
// Per-row state = SEPARATE NAMED arrays (SROA rule, rounds 2-3).
// FUSEG (row-local attn1->gemm2, r10-verified): SHW unions with XS.
template <bool RELU, bool FUSEG>
__global__ __launch_bounds__(256, 2) void k_attn(
    const float* __restrict__ xlp, const float* __restrict__ xr,
    const float* __restrict__ att, const float* __restrict__ alE,
    const float* __restrict__ bias, const unsigned char* __restrict__ mask,
    float* __restrict__ out,
    const float* __restrict__ Wl2, const float* __restrict__ Wr2,
    const float* __restrict__ att2,
    float* __restrict__ xl2, float* __restrict__ xr2, float* __restrict__ alE2)
{
    __shared__ __align__(16) float XS[8192];    // XBUF[4][2][1024] then SHW
    __shared__ float Opart[4][4][4][64];        // [ii][wave][jlgrp][p]
    __shared__ float Lpart[4][4][4][NHEAD];
    __shared__ float RES[4][64];                // FUSEG: block's 4 out rows

    int tid = threadIdx.x;
    int wave = tid >> 6, lane = tid & 63;
    int h = lane & 3, jl = lane >> 2;
    int b = blockIdx.x >> 8;
    int i0 = (blockIdx.x & 255) << 2;

    const float* xlb = xlp + (b << 16);

    // natural head-h slices: at[p] = att[h][p], xr?f[p] = xr[row][h*16+p]
    float at[16], xr0f[16], xr1f[16], xr2f[16], xr3f[16];
    {
        const float* ap = att + (h << 4);
        const float* r0 = xr + (((b << 10) + i0) << 6) + (h << 4);
        const float* r1 = r0 + 64;
        const float* r2 = r0 + 128;
        const float* r3 = r0 + 192;
        #pragma unroll
        for (int c = 0; c < 4; ++c) {
            *(float4*)&at[c << 2]   = *(const float4*)(ap + (c << 2));
            *(float4*)&xr0f[c << 2] = *(const float4*)(r0 + (c << 2));
            *(float4*)&xr1f[c << 2] = *(const float4*)(r1 + (c << 2));
            *(float4*)&xr2f[c << 2] = *(const float4*)(r2 + (c << 2));
            *(float4*)&xr3f[c << 2] = *(const float4*)(r3 + (c << 2));
        }
        #pragma unroll
        for (int p = 0; p < 16; ++p) at[p] *= 0.4f * LOG2E;
    }
    // arE per row, fully in-lane (unchanged)
    float ar0, ar1, ar2, ar3;
    {
        float s0[4], s1[4], s2[4], s3[4];
        #pragma unroll
        for (int c = 0; c < 4; ++c) {
            float t0 = 0.f, t1 = 0.f, t2 = 0.f, t3 = 0.f;
            #pragma unroll
            for (int r = 0; r < 4; ++r) {
                int p = (c << 2) + r;
                float a = at[p];
                t0 = fmaf(a, xr0f[p], t0);
                t1 = fmaf(a, xr1f[p], t1);
                t2 = fmaf(a, xr2f[p], t2);
                t3 = fmaf(a, xr3f[p], t3);
            }
            s0[c] = t0; s1[c] = t1; s2[c] = t2; s3[c] = t3;
        }
        ar0 = 1.5f * ((s0[0] + s0[1]) + (s0[2] + s0[3]));
        ar1 = 1.5f * ((s1[0] + s1[1]) + (s1[2] + s1[3]));
        ar2 = 1.5f * ((s2[0] + s2[1]) + (s2[2] + s2[3]));
        ar3 = 1.5f * ((s3[0] + s3[1]) + (s3[2] + s3[3]));
    }

    // mask bits for j = wave*256 + s*16 + jl (r11 verbatim)
    unsigned mb0, mb1, mb2, mb3;
    {
        const unsigned char* mp = mask + i0 * NN + (wave << 8) + jl;
        int hh = h << 6;                 // (4h)*16 bytes
        unsigned n0 = (unsigned)mp[hh] | ((unsigned)mp[hh + 16] << 1)
                    | ((unsigned)mp[hh + 32] << 2) | ((unsigned)mp[hh + 48] << 3);
        mp += NN;
        unsigned n1 = (unsigned)mp[hh] | ((unsigned)mp[hh + 16] << 1)
                    | ((unsigned)mp[hh + 32] << 2) | ((unsigned)mp[hh + 48] << 3);
        mp += NN;
        unsigned n2 = (unsigned)mp[hh] | ((unsigned)mp[hh + 16] << 1)
                    | ((unsigned)mp[hh + 32] << 2) | ((unsigned)mp[hh + 48] << 3);
        mp += NN;
        unsigned n3 = (unsigned)mp[hh] | ((unsigned)mp[hh + 16] << 1)
                    | ((unsigned)mp[hh + 32] << 2) | ((unsigned)mp[hh + 48] << 3);
        unsigned v0 = n0 << (h << 2), v1 = n1 << (h << 2);
        unsigned v2 = n2 << (h << 2), v3 = n3 << (h << 2);
        v0 |= dpp_movi<0xB1>(v0); v0 |= dpp_movi<0x4E>(v0);
        v1 |= dpp_movi<0xB1>(v1); v1 |= dpp_movi<0x4E>(v1);
        v2 |= dpp_movi<0xB1>(v2); v2 |= dpp_movi<0x4E>(v2);
        v3 |= dpp_movi<0xB1>(v3); v3 |= dpp_movi<0x4E>(v3);
        mb0 = v0; mb1 = v1; mb2 = v2; mb3 = v3;
    }

    float O0[16], O1[16], O2[16], O3[16];
    float lq0 = 0.f, lq1 = 0.f, lq2 = 0.f, lq3 = 0.f;
    #pragma unroll
    for (int p = 0; p < 16; ++p) { O0[p] = 0.f; O1[p] = 0.f; O2[p] = 0.f; O3[p] = 0.f; }

    // --- dense-tile staging setup (addresses r11 verbatim) ---
    const float* tb = xlb + (wave << 14);     // wave's 256 rows (16 tiles)
    float* XB = XS + (wave << 11);            // wave-private [2][1024]
    int l4 = lane << 2;
    int rowoff = (lane >> 4) << 6;
    int sb = (lane & 15) ^ (lane >> 4);
    int A0 = rowoff + (sb << 2);
    int A1 = rowoff + ((sb ^ 4) << 2);
    int qx = (jl >> 2) & 1;
    int rb = (jl << 6) + ((h ^ (jl & 3)) << 2);
    const float* alp = alE + (b << 12) + (wave << 10) + lane;

    // --- 2-deep prologue: tile0->A, tile1->B, write A->buf0, tile2->A ---
    float4 gA0, gA1, gA2, gA3, gB0, gB1, gB2, gB3;
    {
        const float* p = tb + l4;
        gA0 = *(const float4*)p;         gA1 = *(const float4*)(p + 256);
        gA2 = *(const float4*)(p + 512); gA3 = *(const float4*)(p + 768);
        p = tb + 1024 + l4;
        gB0 = *(const float4*)p;         gB1 = *(const float4*)(p + 256);
        gB2 = *(const float4*)(p + 512); gB3 = *(const float4*)(p + 768);
        *(float4*)&XB[A0] = gA0;         *(float4*)&XB[256 + A1] = gA1;
        *(float4*)&XB[512 + A0] = gA2;   *(float4*)&XB[768 + A1] = gA3;
        p = tb + 2048 + l4;
        gA0 = *(const float4*)p;         gA1 = *(const float4*)(p + 256);
        gA2 = *(const float4*)(p + 512); gA3 = *(const float4*)(p + 768);
    }

    #pragma unroll 2
    for (int s = 0; s < 16; ++s) {
        // even s: write B (tile s+1) -> buf((s+1)&1), reload B with s+3.
        // odd  s: same with A.  Flight for a tile = 2 full iterations.
        if ((s & 1) == 0) {
            if (s < 15) {
                float* w = XB + (((s + 1) & 1) << 10);
                *(float4*)&w[A0] = gB0;         *(float4*)&w[256 + A1] = gB1;
                *(float4*)&w[512 + A0] = gB2;   *(float4*)&w[768 + A1] = gB3;
            }
            if (s < 13) {
                const float* p = tb + ((s + 3) << 10) + l4;
                gB0 = *(const float4*)p;         gB1 = *(const float4*)(p + 256);
                gB2 = *(const float4*)(p + 512); gB3 = *(const float4*)(p + 768);
            }
        } else {
            if (s < 15) {
                float* w = XB + (((s + 1) & 1) << 10);
                *(float4*)&w[A0] = gA0;         *(float4*)&w[256 + A1] = gA1;
                *(float4*)&w[512 + A0] = gA2;   *(float4*)&w[768 + A1] = gA3;
            }
            if (s < 13) {
                const float* p = tb + ((s + 3) << 10) + l4;
                gA0 = *(const float4*)p;         gA1 = *(const float4*)(p + 256);
                gA2 = *(const float4*)(p + 512); gA3 = *(const float4*)(p + 768);
            }
        }

        const float* XBr = XB + ((s & 1) << 10);
        float xv[16];
        *(float4*)&xv[0]  = *(const float4*)&XBr[rb + (((0 ^ qx)) << 4)];
        *(float4*)&xv[4]  = *(const float4*)&XBr[rb + (((1 ^ qx)) << 4)];
        *(float4*)&xv[8]  = *(const float4*)&XBr[rb + (((2 ^ qx)) << 4)];
        *(float4*)&xv[12] = *(const float4*)&XBr[rb + (((3 ^ qx)) << 4)];
        float alr = alp[s << 6];
        bool m0 = (mb0 >> s) & 1, m1 = (mb1 >> s) & 1;
        bool m2 = (mb2 >> s) & 1, m3 = (mb3 >> s) & 1;

        float s0[4], s1[4], s2[4], s3[4];
        #pragma unroll
        for (int c = 0; c < 4; ++c) {
            float t0 = 0.f, t1 = 0.f, t2 = 0.f, t3 = 0.f;
            #pragma unroll
            for (int r = 0; r < 4; ++r) {
                int p = (c << 2) + r;
                float a = at[p], xvv = xv[p];
                t0 = fmaf(a, __builtin_fabsf(xr0f[p] + xvv), t0);
                t1 = fmaf(a, __builtin_fabsf(xr1f[p] + xvv), t1);
                t2 = fmaf(a, __builtin_fabsf(xr2f[p] + xvv), t2);
                t3 = fmaf(a, __builtin_fabsf(xr3f[p] + xvv), t3);
            }
            s0[c] = t0; s1[c] = t1; s2[c] = t2; s3[c] = t3;
        }
        float e0 = ((s0[0] + s0[1]) + (s0[2] + s0[3])) + (ar0 + alr);
        float e1 = ((s1[0] + s1[1]) + (s1[2] + s1[3])) + (ar1 + alr);
        float e2 = ((s2[0] + s2[1]) + (s2[2] + s2[3])) + (ar2 + alr);
        float e3 = ((s3[0] + s3[1]) + (s3[2] + s3[3])) + (ar3 + alr);
        float pe0 = m0 ? __builtin_amdgcn_exp2f(e0) : 0.f;
        float pe1 = m1 ? __builtin_amdgcn_exp2f(e1) : 0.f;
        float pe2 = m2 ? __builtin_amdgcn_exp2f(e2) : 0.f;
        float pe3 = m3 ? __builtin_amdgcn_exp2f(e3) : 0.f;
        lq0 += pe0; lq1 += pe1; lq2 += pe2; lq3 += pe3;
        #pragma unroll
        for (int p = 0; p < 16; ++p) {
            float xvv = xv[p];
            O0[p] = fmaf(pe0, xvv, O0[p]);
            O1[p] = fmaf(pe1, xvv, O1[p]);
            O2[p] = fmaf(pe2, xvv, O2[p]);
            O3[p] = fmaf(pe3, xvv, O3[p]);
        }
    }

    if constexpr (FUSEG) {
        __syncthreads();               // all waves done reading XS tiles
        for (int t = tid; t < 4096; t += 256) { XS[t] = Wl2[t]; XS[4096 + t] = Wr2[t]; }
    }

    // reduce over the 4 jl's within each 16-lane DPP row (stride-4 lanes)
    #pragma unroll
    for (int p = 0; p < 16; ++p) {
        O0[p] += dpp_mov<0x114>(O0[p]);  O0[p] += dpp_mov<0x118>(O0[p]);
        O1[p] += dpp_mov<0x114>(O1[p]);  O1[p] += dpp_mov<0x118>(O1[p]);
        O2[p] += dpp_mov<0x114>(O2[p]);  O2[p] += dpp_mov<0x118>(O2[p]);
        O3[p] += dpp_mov<0x114>(O3[p]);  O3[p] += dpp_mov<0x118>(O3[p]);
    }
    lq0 += dpp_mov<0x114>(lq0);  lq0 += dpp_mov<0x118>(lq0);
    lq1 += dpp_mov<0x114>(lq1);  lq1 += dpp_mov<0x118>(lq1);
    lq2 += dpp_mov<0x114>(lq2);  lq2 += dpp_mov<0x118>(lq2);
    lq3 += dpp_mov<0x114>(lq3);  lq3 += dpp_mov<0x118>(lq3);

    if ((lane & 15) >= 12) {             // lanes 12..15 of each DPP row
        int k = lane >> 4;               // jl-group
        #pragma unroll
        for (int c = 0; c < 4; ++c) {
            *(float4*)&Opart[0][wave][k][(h << 4) + (c << 2)] = *(const float4*)&O0[c << 2];
            *(float4*)&Opart[1][wave][k][(h << 4) + (c << 2)] = *(const float4*)&O1[c << 2];
            *(float4*)&Opart[2][wave][k][(h << 4) + (c << 2)] = *(const float4*)&O2[c << 2];
            *(float4*)&Opart[3][wave][k][(h << 4) + (c << 2)] = *(const float4*)&O3[c << 2];
        }
        Lpart[0][wave][k][h] = lq0;
        Lpart[1][wave][k][h] = lq1;
        Lpart[2][wave][k][h] = lq2;
        Lpart[3][wave][k][h] = lq3;
    }
    __syncthreads();                     // covers Opart/Lpart (+ SHW stage)

    {
        int ii = tid >> 6, c = tid & 63;
        float o = 0.f, l = 0.f;
        #pragma unroll
        for (int w = 0; w < 4; ++w)
            #pragma unroll
            for (int k = 0; k < 4; ++k) {
                o += Opart[ii][w][k][c];
                l += Lpart[ii][w][k][c >> 4];
            }
        float res = o / l + bias[c];
        if (RELU) res = fmaxf(res, 0.f);
        if constexpr (FUSEG) {
            RES[ii][c] = res;            // hbuf never touches global
        } else {
            out[((b << 10) + i0 + ii) * D + c] = res;
        }
    }

    if constexpr (FUSEG) {
        __syncthreads();
        // next-layer dual GEMM on this block's 4 rows (row-local dep)
        int ii = tid >> 6, c = tid & 63;
        int rr = (blockIdx.x << 2) + ii;
        float av = att2[c];
        const float* arow = &RES[ii][0];
        float accl = 0.f, accr = 0.f;
        #pragma unroll
        for (int p = 0; p < 64; ++p) {
            float a = arow[p];                    // LDS broadcast read
            accl = fmaf(a, XS[p * 64 + c], accl);
            accr = fmaf(a, XS[4096 + p * 64 + c], accr);
        }
        int cp = (((c >> 2) & 3) << 4) | ((c >> 4) << 2) | (c & 3);
        xl2[rr * 64 + cp] = accl;
        xr2[rr * 64 + c] = accr;
        float t = dpp_rowsum16(accl * av);
        if ((c & 15) == 15) alE2[(rr << 2) | (c >> 4)] = 0.6f * LOG2E * t;
    }
}

extern "C" void kernel_launch(void* const* d_in, const int* in_sizes, int n_in,
                              void* d_out, int out_size, void* d_ws, size_t ws_size,
                              hipStream_t stream) {
    const float* x    = (const float*)d_in[0];
    const float* emb  = (const float*)d_in[1];
    const float* Wl1  = (const float*)d_in[2];
    const float* Wr1  = (const float*)d_in[3];
    const float* att1 = (const float*)d_in[4];
    const float* b1   = (const float*)d_in[5];
    const float* Wl2  = (const float*)d_in[6];
    const float* Wr2  = (const float*)d_in[7];
    const float* att2 = (const float*)d_in[8];
    const float* b2   = (const float*)d_in[9];
    float* out = (float*)d_out;

    unsigned char* mask = (unsigned char*)d_ws;                 // 1MB
    float* xl   = (float*)(mask + NN * NN);                     // 512KB (permuted)
    float* xr   = xl + BB * NN * D;                             // 512KB
    float* xl2  = xr + BB * NN * D;                             // 512KB (permuted)
    float* alE  = xl2 + BB * NN * D;                            // 32KB
    float* xr2  = alE + BB * NN * NHEAD;                        // 512KB
    float* alE2 = xr2 + BB * NN * D;                            // 32KB

    k_mask_gemm<<<256 + BB * NN / 4, 256, 0, stream>>>(emb, mask, x, Wl1, Wr1, att1, xl, xr, alE);

    // attn layer 1 (relu) + fused layer-2 dual GEMM (row-local dependency)
    k_attn<true, true><<<BB * NN / 4, 256, 0, stream>>>(
        xl, xr, att1, alE, b1, mask, xl2 /*unused out*/,
        Wl2, Wr2, att2, xl2, xr2, alE2);

    // attn layer 2 -> final output
    k_attn<false, false><<<BB * NN / 4, 256, 0, stream>>>(
        xl2, xr2, att2, alE2, b2, mask, out,
        Wl2, Wr2, att2, xl2, xr2, alE2 /*unused*/);
}